// Round 16
// baseline (532.795 us; speedup 1.0000x reference)
//
#include <hip/hip_runtime.h>

typedef unsigned short u16;
typedef __attribute__((ext_vector_type(8))) short bf16x8;
typedef __attribute__((ext_vector_type(4))) float f32x4;
typedef __attribute__((ext_vector_type(4))) u16 u16x4;
typedef __attribute__((ext_vector_type(8))) u16 u16x8;

#define DEV static __device__ __forceinline__

DEV u16 f2bf(float f) {
  union { float f; unsigned u; } v; v.f = f;
  unsigned r = (v.u + 0x7fffu + ((v.u >> 16) & 1u)) >> 16;
  return (u16)r;
}

DEV float bf2f(u16 v) { return __int_as_float(((int)v) << 16); }

DEV void gload_lds16(const void* g, void* l) {
  __builtin_amdgcn_global_load_lds(
      (const __attribute__((address_space(1))) unsigned int*)g,
      (__attribute__((address_space(3))) unsigned int*)l, 16, 0, 0);
}

// ---------------------------------------------------------------------------
// 256x256 8-wave MFMA GEMM — m201 8-phase (HEAD GEMM only). Plain C stores.
// ---------------------------------------------------------------------------
#define STGH(buf, mat, half, P, kt) { \
    const int r_ = (half) * 128 + sr0; \
    gload_lds16((P) + (size_t)r_ * K + (kt) + scs, &lds[buf][mat][r_][sc8]); \
    gload_lds16((P) + (size_t)(r_ + 64) * K + (kt) + scs, &lds[buf][mat][r_ + 64][sc8]); }
#define LDB(buf) _Pragma("unroll") for (int n = 0; n < 4; ++n) { \
    const int row = wn * 64 + n * 16 + lr; \
    _Pragma("unroll") for (int kk = 0; kk < 2; ++kk) \
      bfr[n][kk] = *(const bf16x8*)&lds[buf][1][row][(((kk << 2) | lq) ^ (row & 7)) << 3]; }
#define LDA(buf, p) _Pragma("unroll") for (int mi = 0; mi < 2; ++mi) { \
    const int row = wm * 128 + ((p) * 2 + mi) * 16 + lr; \
    _Pragma("unroll") for (int kk = 0; kk < 2; ++kk) \
      af[mi][kk] = *(const bf16x8*)&lds[buf][0][row][(((kk << 2) | lq) ^ (row & 7)) << 3]; }
#define MM(p) __builtin_amdgcn_s_setprio(1); \
  _Pragma("unroll") for (int kk = 0; kk < 2; ++kk) \
  _Pragma("unroll") for (int mi = 0; mi < 2; ++mi) \
  _Pragma("unroll") for (int n = 0; n < 4; ++n) \
    acc[(p) * 2 + mi][n] = __builtin_amdgcn_mfma_f32_16x16x32_bf16(af[mi][kk], bfr[n][kk], acc[(p) * 2 + mi][n], 0, 0, 0); \
  __builtin_amdgcn_s_setprio(0);
#define BAR() { __builtin_amdgcn_s_barrier(); asm volatile("" ::: "memory"); }
#define WLG() { asm volatile("s_waitcnt lgkmcnt(0)" ::: "memory"); __builtin_amdgcn_sched_barrier(0); }
#define VMC(n) asm volatile("s_waitcnt vmcnt(" #n ")" ::: "memory")

__global__ __launch_bounds__(512, 1)
void gemm256(const u16* __restrict__ A, const u16* __restrict__ BT,
             float* __restrict__ C, int M, int N, int K) {
  __shared__ u16 lds[2][2][256][64];   // [buf][A=0,B=1][row][k]
  const int t = threadIdx.x;
  const int l = t & 63;
  const int w = t >> 6;
  const int wm = w >> 2;        // 0..1
  const int wn = w & 3;         // 0..3
  const int lr = l & 15, lq = l >> 4;

  const int gn = N >> 8;
  const int nwg = gn << 3;
  const int orig = blockIdx.y * 8 + blockIdx.x;
  const int q = nwg >> 3;
  const int swz = (orig & 7) * q + (orig >> 3);
  const int bx = swz & 7;
  const int by = swz >> 3;

  const u16* Ap = A + (size_t)bx * 256 * K;
  const u16* Bp = BT + (size_t)by * 256 * K;
  const int sr0 = t >> 3;
  const int sc8 = (t & 7) << 3;
  const int scs = (((t & 7) ^ (sr0 & 7)) << 3);

  f32x4 acc[8][4];
#pragma unroll
  for (int m = 0; m < 8; ++m)
#pragma unroll
    for (int n = 0; n < 4; ++n) acc[m][n] = (f32x4){0.f, 0.f, 0.f, 0.f};

  const int NI = K >> 7;
  STGH(0, 1, 0, Bp, 0) STGH(0, 1, 1, Bp, 0)
  STGH(0, 0, 0, Ap, 0) STGH(0, 0, 1, Ap, 0)
  STGH(1, 1, 0, Bp, 64) STGH(1, 1, 1, Bp, 64)
  VMC(4);
  BAR();

  for (int ip = 0; ip < NI; ++ip) {
    const int k0 = ip << 7;
    const bool m2 = (k0 + 128) < K;
    const bool m3 = (k0 + 192) < K;
    bf16x8 bfr[4][2], af[2][2];
    LDB(0) LDA(0, 0)
    STGH(1, 0, 0, Ap, k0 + 64)
    BAR(); WLG(); MM(0) BAR();
    LDA(0, 1)
    STGH(1, 0, 1, Ap, k0 + 64)
    BAR(); WLG(); MM(1) BAR();
    LDA(0, 2)
    if (m2) STGH(0, 1, 0, Bp, k0 + 128)
    BAR(); WLG(); MM(2) BAR();
    LDA(0, 3)
    if (m2) STGH(0, 1, 1, Bp, k0 + 128)
    BAR(); WLG(); MM(3)
    if (m2) { VMC(4); } else { VMC(0); }
    BAR();
    LDB(1) LDA(1, 0)
    if (m2) STGH(0, 0, 0, Ap, k0 + 128)
    BAR(); WLG(); MM(0) BAR();
    LDA(1, 1)
    if (m2) STGH(0, 0, 1, Ap, k0 + 128)
    BAR(); WLG(); MM(1) BAR();
    LDA(1, 2)
    if (m3) STGH(1, 1, 0, Bp, k0 + 192)
    BAR(); WLG(); MM(2) BAR();
    LDA(1, 3)
    if (m3) STGH(1, 1, 1, Bp, k0 + 192)
    BAR(); WLG(); MM(3)
    if (m3) { VMC(4); } else { VMC(0); }
    BAR();
  }

  const int lg4 = lq * 4;
#pragma unroll
  for (int m = 0; m < 8; ++m) {
    const int grow0 = bx * 256 + wm * 128 + m * 16 + lg4;
#pragma unroll
    for (int n = 0; n < 4; ++n) {
      const int gcol = by * 256 + wn * 64 + n * 16 + lr;
#pragma unroll
      for (int r = 0; r < 4; ++r) {
        const size_t idx = (size_t)(grow0 + r) * N + gcol;
        C[idx] = acc[m][n][r];
      }
    }
  }
}
#undef STGH
#undef LDB
#undef LDA
#undef MM
#undef BAR
#undef WLG
#undef VMC

// ---------------------------------------------------------------------------
// 128x128 BK=64 GEMM.  EPI: 0 = f32 C; 1 = +bias, softplus, bf16 Cbf;
// 2 = plain bf16 Cbf.  gridDim.x MUST be 16; nwg % 8 == 0.
// ---------------------------------------------------------------------------
template<int EPI>
__global__ __launch_bounds__(256)
void gemm_bt(const u16* __restrict__ A, const u16* __restrict__ BT,
             float* __restrict__ C, u16* __restrict__ Cbf,
             const float* __restrict__ bias, int M, int N, int K) {
  __shared__ u16 As[128][64];
  __shared__ u16 Bs[128][64];
  const int t = threadIdx.x;
  const int l = t & 63;
  const int w = t >> 6;
  const int wr = (w >> 1) * 64;
  const int wc = (w & 1) * 64;

  const int nwg = gridDim.x * gridDim.y;
  const int orig = blockIdx.y * gridDim.x + blockIdx.x;
  const int swz = (orig & 7) * (nwg >> 3) + (orig >> 3);
  const int bx = swz & 15;
  const int by = swz >> 4;

  const size_t aoff = (size_t)bx * 128 * K;
  const size_t boff = (size_t)by * 128 * K;
  const int r0 = t >> 3;
  const int c0s = (((t & 7) ^ (r0 & 7)) << 3);
  const int c0l = (t & 7) << 3;
  const int lr = l & 15;
  const int lq = l >> 4;

  f32x4 acc[4][4];
#pragma unroll
  for (int i = 0; i < 4; ++i)
#pragma unroll
    for (int j = 0; j < 4; ++j) acc[i][j] = (f32x4){0.f, 0.f, 0.f, 0.f};

  for (int kt = 0; kt < K; kt += 64) {
    __syncthreads();
#pragma unroll
    for (int i = 0; i < 4; ++i) {
      const int r = r0 + i * 32;
      gload_lds16(A + aoff + (size_t)r * K + kt + c0s, &As[r][c0l]);
      gload_lds16(BT + boff + (size_t)r * K + kt + c0s, &Bs[r][c0l]);
    }
    __syncthreads();
#pragma unroll
    for (int kk = 0; kk < 2; ++kk) {
      bf16x8 af[4], bfr[4];
#pragma unroll
      for (int i = 0; i < 4; ++i) {
        const int row = wr + i * 16 + lr;
        af[i] = *(const bf16x8*)&As[row][(((kk << 2) | lq) ^ (row & 7)) << 3];
      }
#pragma unroll
      for (int j = 0; j < 4; ++j) {
        const int row = wc + j * 16 + lr;
        bfr[j] = *(const bf16x8*)&Bs[row][(((kk << 2) | lq) ^ (row & 7)) << 3];
      }
#pragma unroll
      for (int i = 0; i < 4; ++i)
#pragma unroll
        for (int j = 0; j < 4; ++j)
          acc[i][j] = __builtin_amdgcn_mfma_f32_16x16x32_bf16(af[i], bfr[j], acc[i][j], 0, 0, 0);
    }
  }

  const int lg4 = lq * 4;
#pragma unroll
  for (int i = 0; i < 4; ++i) {
    const int grow0 = bx * 128 + wr + i * 16 + lg4;
#pragma unroll
    for (int j = 0; j < 4; ++j) {
      const int gcol = by * 128 + wc + j * 16 + lr;
      float bv = 0.f;
      if (EPI == 1) bv = bias[gcol];
#pragma unroll
      for (int r = 0; r < 4; ++r) {
        float v = acc[i][j][r];
        if (EPI == 0) {
          C[(size_t)(grow0 + r) * N + gcol] = v;
        } else if (EPI == 1) {
          v += bv;
          v = fmaxf(v, 0.f) + log1pf(expf(-fabsf(v)));   // stable softplus
          Cbf[(size_t)(grow0 + r) * N + gcol] = f2bf(v);
        } else {
          Cbf[(size_t)(grow0 + r) * N + gcol] = f2bf(v);
        }
      }
    }
  }
}

// ---------------------------------------------------------------------------
// x_proj split-K 16: A=ubf[2048,2048], BT=WxT[128,2048] (both ld 2048).
// grid (16, 16): bx = row-tile, ch = K-chunk of 128. Partials to P[r][96]
// (padding cols 96-127 are zeros — not written).
// ---------------------------------------------------------------------------
__global__ __launch_bounds__(256)
void xproj_split(const u16* __restrict__ A, const u16* __restrict__ BT,
                 float* __restrict__ P) {
  __shared__ u16 As[128][64];
  __shared__ u16 Bs[128][64];
  const int t = threadIdx.x;
  const int l = t & 63;
  const int w = t >> 6;
  const int wr = (w >> 1) * 64;
  const int wc = (w & 1) * 64;
  const int bx = blockIdx.x;
  const int ch = blockIdx.y;
  const int kb = ch * 128;

  const size_t aoff = (size_t)bx * 128 * 2048 + kb;
  const int r0 = t >> 3;
  const int c0s = (((t & 7) ^ (r0 & 7)) << 3);
  const int c0l = (t & 7) << 3;
  const int lr = l & 15;
  const int lq = l >> 4;

  f32x4 acc[4][4];
#pragma unroll
  for (int i = 0; i < 4; ++i)
#pragma unroll
    for (int j = 0; j < 4; ++j) acc[i][j] = (f32x4){0.f, 0.f, 0.f, 0.f};

  for (int kt = 0; kt < 128; kt += 64) {
    __syncthreads();
#pragma unroll
    for (int i = 0; i < 4; ++i) {
      const int r = r0 + i * 32;
      gload_lds16(A + aoff + (size_t)r * 2048 + kt + c0s, &As[r][c0l]);
      gload_lds16(BT + (size_t)r * 2048 + kb + kt + c0s, &Bs[r][c0l]);
    }
    __syncthreads();
#pragma unroll
    for (int kk = 0; kk < 2; ++kk) {
      bf16x8 af[4], bfr[4];
#pragma unroll
      for (int i = 0; i < 4; ++i) {
        const int row = wr + i * 16 + lr;
        af[i] = *(const bf16x8*)&As[row][(((kk << 2) | lq) ^ (row & 7)) << 3];
      }
#pragma unroll
      for (int j = 0; j < 4; ++j) {
        const int row = wc + j * 16 + lr;
        bfr[j] = *(const bf16x8*)&Bs[row][(((kk << 2) | lq) ^ (row & 7)) << 3];
      }
#pragma unroll
      for (int i = 0; i < 4; ++i)
#pragma unroll
        for (int j = 0; j < 4; ++j)
          acc[i][j] = __builtin_amdgcn_mfma_f32_16x16x32_bf16(af[i], bfr[j], acc[i][j], 0, 0, 0);
    }
  }

  float* __restrict__ Pc = P + (size_t)ch * 196608;   // 2048*96
  const int lg4 = lq * 4;
#pragma unroll
  for (int i = 0; i < 4; ++i) {
    const int grow0 = bx * 128 + wr + i * 16 + lg4;
#pragma unroll
    for (int j = 0; j < 4; ++j) {
      const int gcol = wc + j * 16 + lr;
      if (gcol < 96) {
#pragma unroll
        for (int r = 0; r < 4; ++r)
          Pc[(size_t)(grow0 + r) * 96 + gcol] = acc[i][j][r];
      }
    }
  }
}

// merge 16 x_proj partials -> dtbf bf16 [r][64] + compact dbc32 f32 [r][32]
// grid 768 blocks x 256 thr over 2048*96 elements.
__global__ __launch_bounds__(256)
void merge_x(const float* __restrict__ P, float* __restrict__ dbc32,
             u16* __restrict__ dtbf) {
  const int idx = blockIdx.x * 256 + threadIdx.x;   // 196608
  float s = 0.f;
#pragma unroll
  for (int ch = 0; ch < 16; ++ch) s += P[(size_t)ch * 196608 + idx];
  const int r = idx / 96, c = idx - r * 96;
  if (c < 64) dtbf[r * 64 + c] = f2bf(s);
  else        dbc32[r * 32 + (c - 64)] = s;
}

// ---------------------------------------------------------------------------
// out_proj split-K 2: A=ybf[2048,2048], BT=WoT[1024,2048] (ld 2048).
// grid (16, 16): bx = row-tile, y&7 = N-tile, y>>3 = K-half of 1024.
// ---------------------------------------------------------------------------
__global__ __launch_bounds__(256)
void outproj_split(const u16* __restrict__ A, const u16* __restrict__ BT,
                   float* __restrict__ P) {
  __shared__ u16 As[128][64];
  __shared__ u16 Bs[128][64];
  const int t = threadIdx.x;
  const int l = t & 63;
  const int w = t >> 6;
  const int wr = (w >> 1) * 64;
  const int wc = (w & 1) * 64;
  const int bx = blockIdx.x;
  const int byn = blockIdx.y & 7;
  const int ch = blockIdx.y >> 3;      // 0..1
  const int kb = ch * 1024;

  const size_t aoff = (size_t)bx * 128 * 2048 + kb;
  const size_t boff = (size_t)byn * 128 * 2048 + kb;
  const int r0 = t >> 3;
  const int c0s = (((t & 7) ^ (r0 & 7)) << 3);
  const int c0l = (t & 7) << 3;
  const int lr = l & 15;
  const int lq = l >> 4;

  f32x4 acc[4][4];
#pragma unroll
  for (int i = 0; i < 4; ++i)
#pragma unroll
    for (int j = 0; j < 4; ++j) acc[i][j] = (f32x4){0.f, 0.f, 0.f, 0.f};

  for (int kt = 0; kt < 1024; kt += 64) {
    __syncthreads();
#pragma unroll
    for (int i = 0; i < 4; ++i) {
      const int r = r0 + i * 32;
      gload_lds16(A + aoff + (size_t)r * 2048 + kt + c0s, &As[r][c0l]);
      gload_lds16(BT + boff + (size_t)r * 2048 + kt + c0s, &Bs[r][c0l]);
    }
    __syncthreads();
#pragma unroll
    for (int kk = 0; kk < 2; ++kk) {
      bf16x8 af[4], bfr[4];
#pragma unroll
      for (int i = 0; i < 4; ++i) {
        const int row = wr + i * 16 + lr;
        af[i] = *(const bf16x8*)&As[row][(((kk << 2) | lq) ^ (row & 7)) << 3];
      }
#pragma unroll
      for (int j = 0; j < 4; ++j) {
        const int row = wc + j * 16 + lr;
        bfr[j] = *(const bf16x8*)&Bs[row][(((kk << 2) | lq) ^ (row & 7)) << 3];
      }
#pragma unroll
      for (int i = 0; i < 4; ++i)
#pragma unroll
        for (int j = 0; j < 4; ++j)
          acc[i][j] = __builtin_amdgcn_mfma_f32_16x16x32_bf16(af[i], bfr[j], acc[i][j], 0, 0, 0);
    }
  }

  float* __restrict__ Pc = P + (size_t)ch * 2097152;
  const int lg4 = lq * 4;
#pragma unroll
  for (int i = 0; i < 4; ++i) {
    const int grow0 = bx * 128 + wr + i * 16 + lg4;
#pragma unroll
    for (int j = 0; j < 4; ++j) {
      const int gcol = byn * 128 + wc + j * 16 + lr;
#pragma unroll
      for (int r = 0; r < 4; ++r)
        Pc[(size_t)(grow0 + r) * 1024 + gcol] = acc[i][j][r];
    }
  }
}

// layer-1 merge: xbf = bf16(p0 + p1)
__global__ __launch_bounds__(256)
void merge_o1(const float* __restrict__ P, u16* __restrict__ xbf) {
  const int i4 = (blockIdx.x * 256 + threadIdx.x) * 4;   // 2048 blocks
  const float4 a = *(const float4*)(P + i4);
  const float4 b = *(const float4*)(P + 2097152 + i4);
  u16x4 o = { f2bf(a.x + b.x), f2bf(a.y + b.y), f2bf(a.z + b.z), f2bf(a.w + b.w) };
  *(u16x4*)(xbf + i4) = o;
}

// layer-2 merge + final LayerNorm fused: xlnbf = bf16(LN(p0+p1))
__global__ __launch_bounds__(256)
void merge_o2_ln(const float* __restrict__ P, const float* __restrict__ g,
                 const float* __restrict__ bta, u16* __restrict__ out) {
  __shared__ float red1[4], red2[4];
  const int r = blockIdx.x;
  const int tid = threadIdx.x;
  const int lane = tid & 63, wid = tid >> 6;
  const int c4 = tid * 4;
  const float4 a = *(const float4*)(P + (size_t)r * 1024 + c4);
  const float4 b = *(const float4*)(P + 2097152 + (size_t)r * 1024 + c4);
  float4 v = { a.x + b.x, a.y + b.y, a.z + b.z, a.w + b.w };
  float s = v.x + v.y + v.z + v.w;
#pragma unroll
  for (int m = 1; m < 64; m <<= 1) s += __shfl_xor(s, m, 64);
  if (lane == 0) red1[wid] = s;
  __syncthreads();
  const float mu = (red1[0] + red1[1] + red1[2] + red1[3]) * (1.f / 1024.f);
  const float d0 = v.x - mu, d1 = v.y - mu, d2 = v.z - mu, d3 = v.w - mu;
  float q = d0 * d0 + d1 * d1 + d2 * d2 + d3 * d3;
#pragma unroll
  for (int m = 1; m < 64; m <<= 1) q += __shfl_xor(q, m, 64);
  if (lane == 0) red2[wid] = q;
  __syncthreads();
  const float rs = rsqrtf((red2[0] + red2[1] + red2[2] + red2[3]) * (1.f / 1024.f) + 1e-5f);
  const float4 gv = *(const float4*)(g + c4);
  const float4 bv = *(const float4*)(bta + c4);
  u16x4 o = { f2bf(d0 * rs * gv.x + bv.x), f2bf(d1 * rs * gv.y + bv.y),
              f2bf(d2 * rs * gv.z + bv.z), f2bf(d3 * rs * gv.w + bv.w) };
  *(u16x4*)(out + (size_t)r * 1024 + c4) = o;
}

// ---------------------------------------------------------------------------
// mega prep batch: 64x64 tiles; 256B-contiguous NT reads, u16x8 stores.
// tx<0: embed gather (lt = row).
// ---------------------------------------------------------------------------
struct TBatch {
  const float* src[10];
  u16* dst[10];
  int K[10], N[10], tx[10];
  int start[11];
  int njobs;
  const int* ids;
};

__global__ __launch_bounds__(256)
void transpose_batch(TBatch tb) {
  const int tile = blockIdx.x;
  int j = 0;
  while (j + 1 < tb.njobs && tile >= tb.start[j + 1]) ++j;
  const int lt = tile - tb.start[j];

  if (tb.tx[j] < 0) {   // embed gather: row lt, 1024 cols via float4
    const int c = threadIdx.x * 4;
    const int id = tb.ids[lt];
    const float4 v = *(const float4*)(tb.src[j] + (size_t)id * 1024 + c);
    u16x4 o = { f2bf(v.x), f2bf(v.y), f2bf(v.z), f2bf(v.w) };
    *(u16x4*)(tb.dst[j] + (size_t)lt * 1024 + c) = o;
    return;
  }

  const int K = tb.K[j];
  const int N = tb.N[j];
  const int kb = (lt % tb.tx[j]) * 64;
  const int nb = (lt / tb.tx[j]) * 64;
  const float* __restrict__ in = tb.src[j];
  u16* __restrict__ out = tb.dst[j];

  __shared__ float ts[64][65];
  const int rr = threadIdx.x >> 4;        // 0..15
  const int cc = (threadIdx.x & 15) * 4;  // 0..60
  const int gn = nb + cc;
#pragma unroll
  for (int s = 0; s < 4; ++s) {
    const int k = kb + s * 16 + rr;
    f32x4 v = { 0.f, 0.f, 0.f, 0.f };
    if (gn < N) v = __builtin_nontemporal_load((const f32x4*)(in + (size_t)k * N + gn));
    ts[s * 16 + rr][cc + 0] = v[0];
    ts[s * 16 + rr][cc + 1] = v[1];
    ts[s * 16 + rr][cc + 2] = v[2];
    ts[s * 16 + rr][cc + 3] = v[3];
  }
  __syncthreads();
  const int k8 = (threadIdx.x & 7) * 8;
#pragma unroll
  for (int s = 0; s < 2; ++s) {
    const int nl = (threadIdx.x >> 3) + s * 32;   // 0..63
    u16x8 o;
#pragma unroll
    for (int i = 0; i < 8; ++i) o[i] = f2bf(ts[k8 + i][nl]);
    *(u16x8*)(out + (size_t)(nb + nl) * K + kb + k8) = o;
  }
}

// u = silu(causal_conv(xin) + cb) -> bf16.  xz is bf16. 4 ch/thread.
__global__ __launch_bounds__(256)
void conv_silu4(const u16* __restrict__ xzb, const float* __restrict__ cw,
                const float* __restrict__ cb, u16* __restrict__ ubf) {
  const int i4 = (blockIdx.x * 256 + threadIdx.x) * 4;   // grid 4096
  const int d = i4 & 2047;
  const int r = i4 >> 11;
  const int t = r & 1023;
  float4 acc = *(const float4*)(cb + d);
  const float4 w0 = *(const float4*)(cw + (d + 0) * 4);
  const float4 w1 = *(const float4*)(cw + (d + 1) * 4);
  const float4 w2 = *(const float4*)(cw + (d + 2) * 4);
  const float4 w3 = *(const float4*)(cw + (d + 3) * 4);
#pragma unroll
  for (int k = 0; k < 4; ++k) {
    const int tt = t - 3 + k;
    if (tt >= 0) {
      const u16x4 x4 = *(const u16x4*)(xzb + (size_t)(r - 3 + k) * 4096 + d);
      acc.x = fmaf(bf2f(x4[0]), ((const float*)&w0)[k], acc.x);
      acc.y = fmaf(bf2f(x4[1]), ((const float*)&w1)[k], acc.y);
      acc.z = fmaf(bf2f(x4[2]), ((const float*)&w2)[k], acc.z);
      acc.w = fmaf(bf2f(x4[3]), ((const float*)&w3)[k], acc.w);
    }
  }
  u16x4 o = { f2bf(acc.x / (1.f + __expf(-acc.x))), f2bf(acc.y / (1.f + __expf(-acc.y))),
              f2bf(acc.z / (1.f + __expf(-acc.z))), f2bf(acc.w / (1.f + __expf(-acc.w))) };
  *(u16x4*)(ubf + i4) = o;
}

// ---------------------------------------------------------------------------
// selective scan, n-in-registers; delta/u/z read as bf16 (coalesced 2B/lane).
// 32 chunks x 32 steps; grid = 2b x 8dt x 32ch = 512 blocks (2 blocks/CU).
// dbc32 compact layout [r][32]: B = cols 0-15, C = cols 16-31.
// ---------------------------------------------------------------------------
__global__ __launch_bounds__(256)
void scan_pass1(const u16* __restrict__ deltab, const u16* __restrict__ ub,
                const float* __restrict__ dbc32, const float* __restrict__ A_log,
                float* __restrict__ Pb, float* __restrict__ Qb) {
  const int blk = blockIdx.x;
  const int ch = blk & 31;
  if (ch == 31) return;          // last chunk's (P,Q) never consumed
  const int dt = (blk >> 5) & 7;
  const int b = blk >> 8;
  const int d = dt * 256 + threadIdx.x;

  float Ac[16], h[16], P[16];
#pragma unroll
  for (int n = 0; n < 16; ++n) {
    Ac[n] = -expf(A_log[d * 16 + n]) * 1.44269504f;
    h[n] = 0.f;
    P[n] = 1.f;
  }
  const int r0 = b * 1024 + ch * 32;
  for (int j = 0; j < 32; ++j) {
    const size_t r = r0 + j;
    const float dlt = bf2f(deltab[r * 2048 + d]);
    const float uu = bf2f(ub[r * 2048 + d]);
    const float du = dlt * uu;
    const float4 B0 = *(const float4*)(dbc32 + r * 32 + 0);
    const float4 B1 = *(const float4*)(dbc32 + r * 32 + 4);
    const float4 B2 = *(const float4*)(dbc32 + r * 32 + 8);
    const float4 B3 = *(const float4*)(dbc32 + r * 32 + 12);
    const float Bv[16] = { B0.x, B0.y, B0.z, B0.w, B1.x, B1.y, B1.z, B1.w,
                           B2.x, B2.y, B2.z, B2.w, B3.x, B3.y, B3.z, B3.w };
#pragma unroll
    for (int n = 0; n < 16; ++n) {
      const float da = exp2f(dlt * Ac[n]);
      P[n] *= da;
      h[n] = fmaf(da, h[n], du * Bv[n]);
    }
  }
  const size_t o = ((size_t)ch * 4096 + b * 2048 + d) * 16;
#pragma unroll
  for (int n = 0; n < 16; ++n) { Pb[o + n] = P[n]; Qb[o + n] = h[n]; }
}

// fold chunk (P,Q) into per-chunk entry states: Hp[ch] = state entering ch.
// 65536 threads, fully coalesced; same fold order as before.
__global__ __launch_bounds__(256)
void scan_prefix(const float* __restrict__ Pb, const float* __restrict__ Qb,
                 float* __restrict__ Hp) {
  const int tid = blockIdx.x * 256 + threadIdx.x;   // 65536
  float h = 0.f;
  Hp[tid] = 0.f;
  for (int ch = 0; ch < 31; ++ch) {
    const size_t o = (size_t)ch * 65536 + tid;
    h = fmaf(Pb[o], h, Qb[o]);
    Hp[o + 65536] = h;
  }
}

__global__ __launch_bounds__(256)
void scan_pass2(const u16* __restrict__ deltab, const u16* __restrict__ ub,
                const float* __restrict__ dbc32, const u16* __restrict__ xzb,
                const float* __restrict__ A_log, const float* __restrict__ Dp,
                const float* __restrict__ Hp, u16* __restrict__ ybf) {
  const int blk = blockIdx.x;
  const int ch = blk & 31;
  const int dt = (blk >> 5) & 7;
  const int b = blk >> 8;
  const int d = dt * 256 + threadIdx.x;

  float Ac[16], h[16];
  const size_t ho = ((size_t)ch * 4096 + b * 2048 + d) * 16;
#pragma unroll
  for (int n = 0; n < 16; ++n) {
    Ac[n] = -expf(A_log[d * 16 + n]) * 1.44269504f;
    h[n] = Hp[ho + n];
  }
  const float Dd = Dp[d];

  const int r0 = b * 1024 + ch * 32;
  for (int j = 0; j < 32; ++j) {
    const size_t r = r0 + j;
    const float dlt = bf2f(deltab[r * 2048 + d]);
    const float uu = bf2f(ub[r * 2048 + d]);
    const float zz = bf2f(xzb[r * 4096 + 2048 + d]);
    const float du = dlt * uu;
    const float4 B0 = *(const float4*)(dbc32 + r * 32 + 0);
    const float4 B1 = *(const float4*)(dbc32 + r * 32 + 4);
    const float4 B2 = *(const float4*)(dbc32 + r * 32 + 8);
    const float4 B3 = *(const float4*)(dbc32 + r * 32 + 12);
    const float4 C0 = *(const float4*)(dbc32 + r * 32 + 16);
    const float4 C1 = *(const float4*)(dbc32 + r * 32 + 20);
    const float4 C2 = *(const float4*)(dbc32 + r * 32 + 24);
    const float4 C3 = *(const float4*)(dbc32 + r * 32 + 28);
    const float Bv[16] = { B0.x, B0.y, B0.z, B0.w, B1.x, B1.y, B1.z, B1.w,
                           B2.x, B2.y, B2.z, B2.w, B3.x, B3.y, B3.z, B3.w };
    const float Cv[16] = { C0.x, C0.y, C0.z, C0.w, C1.x, C1.y, C1.z, C1.w,
                           C2.x, C2.y, C2.z, C2.w, C3.x, C3.y, C3.z, C3.w };
    float p0 = 0.f, p1 = 0.f, p2 = 0.f, p3 = 0.f;
#pragma unroll
    for (int n = 0; n < 16; n += 4) {
      float da;
      da = exp2f(dlt * Ac[n + 0]); h[n + 0] = fmaf(da, h[n + 0], du * Bv[n + 0]); p0 = fmaf(h[n + 0], Cv[n + 0], p0);
      da = exp2f(dlt * Ac[n + 1]); h[n + 1] = fmaf(da, h[n + 1], du * Bv[n + 1]); p1 = fmaf(h[n + 1], Cv[n + 1], p1);
      da = exp2f(dlt * Ac[n + 2]); h[n + 2] = fmaf(da, h[n + 2], du * Bv[n + 2]); p2 = fmaf(h[n + 2], Cv[n + 2], p2);
      da = exp2f(dlt * Ac[n + 3]); h[n + 3] = fmaf(da, h[n + 3], du * Bv[n + 3]); p3 = fmaf(h[n + 3], Cv[n + 3], p3);
    }
    const float p = (p0 + p1) + (p2 + p3);
    const float yv = (p + uu * Dd) * (zz / (1.f + __expf(-zz)));
    ybf[r * 2048 + d] = f2bf(yv);
  }
}

// ---------------------------------------------------------------------------
extern "C" void kernel_launch(void* const* d_in, const int* in_sizes, int n_in,
                              void* d_out, int out_size, void* d_ws, size_t ws_size,
                              hipStream_t stream) {
  (void)in_sizes; (void)n_in; (void)out_size; (void)ws_size;
  const int*   ids      = (const int*)d_in[0];
  const float* embed    = (const float*)d_in[1];
  const float* in_proj  = (const float*)d_in[2];
  const float* conv_w   = (const float*)d_in[3];
  const float* conv_b   = (const float*)d_in[4];
  const float* x_proj   = (const float*)d_in[5];
  const float* dt_w     = (const float*)d_in[6];
  const float* dt_b     = (const float*)d_in[7];
  const float* A_log    = (const float*)d_in[8];
  const float* Dp       = (const float*)d_in[9];
  const float* out_proj = (const float*)d_in[10];
  const float* ln_g     = (const float*)d_in[11];
  const float* ln_bta   = (const float*)d_in[12];
  const float* head     = (const float*)d_in[13];

  // f32 scratch inside d_out (all consumed before head GEMM overwrites)
  float* fout  = (float*)d_out;
  float* dbc32 = fout + 16777216;   // 65,536
  float* Pb    = fout + 17039360;   // 2,097,152
  float* Qb    = fout + 19136512;   // 2,097,152
  float* Hp    = fout + 21233664;   // 2,097,152
  float* xpp   = fout + 23330816;   // 16 * 196,608 = 3,145,728
  float* opp   = fout + 26476544;   // 2 * 2,097,152 = 4,194,304 (ends 30,670,848)

  // bf16 scratch in the dead tail of d_out (dead before head GEMM writes)
  u16* tail = (u16*)(fout + 31000000);
  u16* WiT[2]  = { tail,                tail + 4194304 };
  u16* WxT[2]  = { tail + 8388608,      tail + 8650752 };
  u16* WdtT[2] = { tail + 8912896,      tail + 9043968 };
  u16* WoT[2]  = { tail + 9175040,      tail + 11272192 };
  u16* dbf     = tail + 13369344;      // 4,194,304 u16 (bf16 delta)
  u16* xzb     = tail + 17563648;      // 8,388,608 u16 (ends 25,952,256 u16)

  // bf16 scratch in d_ws
  char* wp = (char*)d_ws;
  u16* headT = (u16*)wp; wp += (size_t)32000 * 1024 * 2;
  u16* xbf   = (u16*)wp; wp += (size_t)2048 * 1024 * 2;
  u16* ubf   = (u16*)wp; wp += (size_t)2048 * 2048 * 2;
  u16* dtbf  = (u16*)wp; wp += (size_t)2048 * 64 * 2;
  u16* ybf   = (u16*)wp; wp += (size_t)2048 * 2048 * 2;
  u16* xlnbf = (u16*)wp; wp += (size_t)2048 * 1024 * 2;

  const dim3 tb(256);
  const dim3 tb5(512);

  // ---- one mega prep launch: head + all layer weights + embed gather ----
  TBatch t{};
  int nj = 0, acc = 0;
  t.ids = ids;
  t.src[nj] = head; t.dst[nj] = headT;
  t.K[nj] = 1024; t.N[nj] = 32000; t.tx[nj] = 16;
  t.start[nj] = acc; acc += 16 * 500; ++nj;
  for (int i = 0; i < 2; ++i) {
    t.src[nj] = in_proj + (size_t)i * 1024 * 4096; t.dst[nj] = WiT[i];
    t.K[nj] = 1024; t.N[nj] = 4096; t.tx[nj] = 16;
    t.start[nj] = acc; acc += 16 * 64; ++nj;
    t.src[nj] = x_proj + (size_t)i * 2048 * 96; t.dst[nj] = WxT[i];
    t.K[nj] = 2048; t.N[nj] = 96; t.tx[nj] = 32;
    t.start[nj] = acc; acc += 32 * 2; ++nj;
    t.src[nj] = dt_w + (size_t)i * 64 * 2048; t.dst[nj] = WdtT[i];
    t.K[nj] = 64; t.N[nj] = 2048; t.tx[nj] = 1;
    t.start[nj] = acc; acc += 1 * 32; ++nj;
    t.src[nj] = out_proj + (size_t)i * 2048 * 1024; t.dst[nj] = WoT[i];
    t.K[nj] = 2048; t.N[nj] = 1024; t.tx[nj] = 32;
    t.start[nj] = acc; acc += 32 * 16; ++nj;
  }
  t.src[nj] = embed; t.dst[nj] = xbf;
  t.K[nj] = 0; t.N[nj] = 0; t.tx[nj] = -1;
  t.start[nj] = acc; acc += 2048; ++nj;
  t.start[nj] = acc;
  t.njobs = nj;
  transpose_batch<<<acc, tb, 0, stream>>>(t);

  for (int i = 0; i < 2; ++i) {
    gemm_bt<2><<<dim3(16, 32), tb, 0, stream>>>(xbf, WiT[i], nullptr, xzb, nullptr, 2048, 4096, 1024);
    conv_silu4<<<4096, tb, 0, stream>>>(xzb, conv_w + i * 2048 * 4, conv_b + i * 2048, ubf);
    xproj_split<<<dim3(16, 16), tb, 0, stream>>>(ubf, WxT[i], xpp);
    merge_x<<<768, tb, 0, stream>>>(xpp, dbc32, dtbf);
    gemm_bt<1><<<dim3(16, 16), tb, 0, stream>>>(dtbf, WdtT[i], nullptr, dbf, dt_b + i * 2048, 2048, 2048, 64);
    scan_pass1<<<512, tb, 0, stream>>>(dbf, ubf, dbc32, A_log + i * 2048 * 16, Pb, Qb);
    scan_prefix<<<256, tb, 0, stream>>>(Pb, Qb, Hp);
    scan_pass2<<<512, tb, 0, stream>>>(dbf, ubf, dbc32, xzb, A_log + i * 2048 * 16, Dp + i * 2048, Hp, ybf);
    outproj_split<<<dim3(16, 16), tb, 0, stream>>>(ybf, WoT[i], opp);
    if (i == 0) {
      merge_o1<<<2048, tb, 0, stream>>>(opp, xbf);
    } else {
      merge_o2_ln<<<2048, tb, 0, stream>>>(opp, ln_g, ln_bta, xlnbf);
    }
  }

  gemm256<<<dim3(8, 125), tb5, 0, stream>>>(xlnbf, headT, fout, 2048, 32000, 1024);
}

// Round 17
// 528.599 us; speedup vs baseline: 1.0079x; 1.0079x over previous
//
#include <hip/hip_runtime.h>

typedef unsigned short u16;
typedef __attribute__((ext_vector_type(8))) short bf16x8;
typedef __attribute__((ext_vector_type(4))) float f32x4;
typedef __attribute__((ext_vector_type(4))) u16 u16x4;
typedef __attribute__((ext_vector_type(8))) u16 u16x8;

#define DEV static __device__ __forceinline__

DEV u16 f2bf(float f) {
  union { float f; unsigned u; } v; v.f = f;
  unsigned r = (v.u + 0x7fffu + ((v.u >> 16) & 1u)) >> 16;
  return (u16)r;
}

DEV float bf2f(u16 v) { return __int_as_float(((int)v) << 16); }

DEV void gload_lds16(const void* g, void* l) {
  __builtin_amdgcn_global_load_lds(
      (const __attribute__((address_space(1))) unsigned int*)g,
      (__attribute__((address_space(3))) unsigned int*)l, 16, 0, 0);
}

// ---------------------------------------------------------------------------
// 256x256 8-wave MFMA GEMM — m201 8-phase (HEAD GEMM only). Plain C stores.
// ---------------------------------------------------------------------------
#define STGH(buf, mat, half, P, kt) { \
    const int r_ = (half) * 128 + sr0; \
    gload_lds16((P) + (size_t)r_ * K + (kt) + scs, &lds[buf][mat][r_][sc8]); \
    gload_lds16((P) + (size_t)(r_ + 64) * K + (kt) + scs, &lds[buf][mat][r_ + 64][sc8]); }
#define LDB(buf) _Pragma("unroll") for (int n = 0; n < 4; ++n) { \
    const int row = wn * 64 + n * 16 + lr; \
    _Pragma("unroll") for (int kk = 0; kk < 2; ++kk) \
      bfr[n][kk] = *(const bf16x8*)&lds[buf][1][row][(((kk << 2) | lq) ^ (row & 7)) << 3]; }
#define LDA(buf, p) _Pragma("unroll") for (int mi = 0; mi < 2; ++mi) { \
    const int row = wm * 128 + ((p) * 2 + mi) * 16 + lr; \
    _Pragma("unroll") for (int kk = 0; kk < 2; ++kk) \
      af[mi][kk] = *(const bf16x8*)&lds[buf][0][row][(((kk << 2) | lq) ^ (row & 7)) << 3]; }
#define MM(p) __builtin_amdgcn_s_setprio(1); \
  _Pragma("unroll") for (int kk = 0; kk < 2; ++kk) \
  _Pragma("unroll") for (int mi = 0; mi < 2; ++mi) \
  _Pragma("unroll") for (int n = 0; n < 4; ++n) \
    acc[(p) * 2 + mi][n] = __builtin_amdgcn_mfma_f32_16x16x32_bf16(af[mi][kk], bfr[n][kk], acc[(p) * 2 + mi][n], 0, 0, 0); \
  __builtin_amdgcn_s_setprio(0);
#define BAR() { __builtin_amdgcn_s_barrier(); asm volatile("" ::: "memory"); }
#define WLG() { asm volatile("s_waitcnt lgkmcnt(0)" ::: "memory"); __builtin_amdgcn_sched_barrier(0); }
#define VMC(n) asm volatile("s_waitcnt vmcnt(" #n ")" ::: "memory")

__global__ __launch_bounds__(512, 1)
void gemm256(const u16* __restrict__ A, const u16* __restrict__ BT,
             float* __restrict__ C, int M, int N, int K) {
  __shared__ u16 lds[2][2][256][64];   // [buf][A=0,B=1][row][k]
  const int t = threadIdx.x;
  const int l = t & 63;
  const int w = t >> 6;
  const int wm = w >> 2;        // 0..1
  const int wn = w & 3;         // 0..3
  const int lr = l & 15, lq = l >> 4;

  const int gn = N >> 8;
  const int nwg = gn << 3;
  const int orig = blockIdx.y * 8 + blockIdx.x;
  const int q = nwg >> 3;
  const int swz = (orig & 7) * q + (orig >> 3);
  const int bx = swz & 7;
  const int by = swz >> 3;

  const u16* Ap = A + (size_t)bx * 256 * K;
  const u16* Bp = BT + (size_t)by * 256 * K;
  const int sr0 = t >> 3;
  const int sc8 = (t & 7) << 3;
  const int scs = (((t & 7) ^ (sr0 & 7)) << 3);

  f32x4 acc[8][4];
#pragma unroll
  for (int m = 0; m < 8; ++m)
#pragma unroll
    for (int n = 0; n < 4; ++n) acc[m][n] = (f32x4){0.f, 0.f, 0.f, 0.f};

  const int NI = K >> 7;
  STGH(0, 1, 0, Bp, 0) STGH(0, 1, 1, Bp, 0)
  STGH(0, 0, 0, Ap, 0) STGH(0, 0, 1, Ap, 0)
  STGH(1, 1, 0, Bp, 64) STGH(1, 1, 1, Bp, 64)
  VMC(4);
  BAR();

  for (int ip = 0; ip < NI; ++ip) {
    const int k0 = ip << 7;
    const bool m2 = (k0 + 128) < K;
    const bool m3 = (k0 + 192) < K;
    bf16x8 bfr[4][2], af[2][2];
    LDB(0) LDA(0, 0)
    STGH(1, 0, 0, Ap, k0 + 64)
    BAR(); WLG(); MM(0) BAR();
    LDA(0, 1)
    STGH(1, 0, 1, Ap, k0 + 64)
    BAR(); WLG(); MM(1) BAR();
    LDA(0, 2)
    if (m2) STGH(0, 1, 0, Bp, k0 + 128)
    BAR(); WLG(); MM(2) BAR();
    LDA(0, 3)
    if (m2) STGH(0, 1, 1, Bp, k0 + 128)
    BAR(); WLG(); MM(3)
    if (m2) { VMC(4); } else { VMC(0); }
    BAR();
    LDB(1) LDA(1, 0)
    if (m2) STGH(0, 0, 0, Ap, k0 + 128)
    BAR(); WLG(); MM(0) BAR();
    LDA(1, 1)
    if (m2) STGH(0, 0, 1, Ap, k0 + 128)
    BAR(); WLG(); MM(1) BAR();
    LDA(1, 2)
    if (m3) STGH(1, 1, 0, Bp, k0 + 192)
    BAR(); WLG(); MM(2) BAR();
    LDA(1, 3)
    if (m3) STGH(1, 1, 1, Bp, k0 + 192)
    BAR(); WLG(); MM(3)
    if (m3) { VMC(4); } else { VMC(0); }
    BAR();
  }

  const int lg4 = lq * 4;
#pragma unroll
  for (int m = 0; m < 8; ++m) {
    const int grow0 = bx * 256 + wm * 128 + m * 16 + lg4;
#pragma unroll
    for (int n = 0; n < 4; ++n) {
      const int gcol = by * 256 + wn * 64 + n * 16 + lr;
#pragma unroll
      for (int r = 0; r < 4; ++r) {
        const size_t idx = (size_t)(grow0 + r) * N + gcol;
        C[idx] = acc[m][n][r];
      }
    }
  }
}
#undef STGH
#undef LDB
#undef LDA
#undef MM
#undef BAR
#undef WLG
#undef VMC

// ---------------------------------------------------------------------------
// 128x128 BK=64 GEMM.  EPI: 0 = f32 C; 1 = +bias, softplus, bf16 Cbf;
// 2 = plain bf16 Cbf.  gridDim.x MUST be 16; nwg % 8 == 0.
// ---------------------------------------------------------------------------
template<int EPI>
__global__ __launch_bounds__(256)
void gemm_bt(const u16* __restrict__ A, const u16* __restrict__ BT,
             float* __restrict__ C, u16* __restrict__ Cbf,
             const float* __restrict__ bias, int M, int N, int K) {
  __shared__ u16 As[128][64];
  __shared__ u16 Bs[128][64];
  const int t = threadIdx.x;
  const int l = t & 63;
  const int w = t >> 6;
  const int wr = (w >> 1) * 64;
  const int wc = (w & 1) * 64;

  const int nwg = gridDim.x * gridDim.y;
  const int orig = blockIdx.y * gridDim.x + blockIdx.x;
  const int swz = (orig & 7) * (nwg >> 3) + (orig >> 3);
  const int bx = swz & 15;
  const int by = swz >> 4;

  const size_t aoff = (size_t)bx * 128 * K;
  const size_t boff = (size_t)by * 128 * K;
  const int r0 = t >> 3;
  const int c0s = (((t & 7) ^ (r0 & 7)) << 3);
  const int c0l = (t & 7) << 3;
  const int lr = l & 15;
  const int lq = l >> 4;

  f32x4 acc[4][4];
#pragma unroll
  for (int i = 0; i < 4; ++i)
#pragma unroll
    for (int j = 0; j < 4; ++j) acc[i][j] = (f32x4){0.f, 0.f, 0.f, 0.f};

  for (int kt = 0; kt < K; kt += 64) {
    __syncthreads();
#pragma unroll
    for (int i = 0; i < 4; ++i) {
      const int r = r0 + i * 32;
      gload_lds16(A + aoff + (size_t)r * K + kt + c0s, &As[r][c0l]);
      gload_lds16(BT + boff + (size_t)r * K + kt + c0s, &Bs[r][c0l]);
    }
    __syncthreads();
#pragma unroll
    for (int kk = 0; kk < 2; ++kk) {
      bf16x8 af[4], bfr[4];
#pragma unroll
      for (int i = 0; i < 4; ++i) {
        const int row = wr + i * 16 + lr;
        af[i] = *(const bf16x8*)&As[row][(((kk << 2) | lq) ^ (row & 7)) << 3];
      }
#pragma unroll
      for (int j = 0; j < 4; ++j) {
        const int row = wc + j * 16 + lr;
        bfr[j] = *(const bf16x8*)&Bs[row][(((kk << 2) | lq) ^ (row & 7)) << 3];
      }
#pragma unroll
      for (int i = 0; i < 4; ++i)
#pragma unroll
        for (int j = 0; j < 4; ++j)
          acc[i][j] = __builtin_amdgcn_mfma_f32_16x16x32_bf16(af[i], bfr[j], acc[i][j], 0, 0, 0);
    }
  }

  const int lg4 = lq * 4;
#pragma unroll
  for (int i = 0; i < 4; ++i) {
    const int grow0 = bx * 128 + wr + i * 16 + lg4;
#pragma unroll
    for (int j = 0; j < 4; ++j) {
      const int gcol = by * 128 + wc + j * 16 + lr;
      float bv = 0.f;
      if (EPI == 1) bv = bias[gcol];
#pragma unroll
      for (int r = 0; r < 4; ++r) {
        float v = acc[i][j][r];
        if (EPI == 0) {
          C[(size_t)(grow0 + r) * N + gcol] = v;
        } else if (EPI == 1) {
          v += bv;
          v = fmaxf(v, 0.f) + log1pf(expf(-fabsf(v)));   // stable softplus
          Cbf[(size_t)(grow0 + r) * N + gcol] = f2bf(v);
        } else {
          Cbf[(size_t)(grow0 + r) * N + gcol] = f2bf(v);
        }
      }
    }
  }
}

// ---------------------------------------------------------------------------
// x_proj split-K 16: A=ubf[2048,2048], BT=WxT[128,2048] (both ld 2048).
// grid (16, 16): bx = row-tile, ch = K-chunk of 128. Partials to P[r][96]
// (padding cols 96-127 are zeros — not written).
// ---------------------------------------------------------------------------
__global__ __launch_bounds__(256)
void xproj_split(const u16* __restrict__ A, const u16* __restrict__ BT,
                 float* __restrict__ P) {
  __shared__ u16 As[128][64];
  __shared__ u16 Bs[128][64];
  const int t = threadIdx.x;
  const int l = t & 63;
  const int w = t >> 6;
  const int wr = (w >> 1) * 64;
  const int wc = (w & 1) * 64;
  const int bx = blockIdx.x;
  const int ch = blockIdx.y;
  const int kb = ch * 128;

  const size_t aoff = (size_t)bx * 128 * 2048 + kb;
  const int r0 = t >> 3;
  const int c0s = (((t & 7) ^ (r0 & 7)) << 3);
  const int c0l = (t & 7) << 3;
  const int lr = l & 15;
  const int lq = l >> 4;

  f32x4 acc[4][4];
#pragma unroll
  for (int i = 0; i < 4; ++i)
#pragma unroll
    for (int j = 0; j < 4; ++j) acc[i][j] = (f32x4){0.f, 0.f, 0.f, 0.f};

  for (int kt = 0; kt < 128; kt += 64) {
    __syncthreads();
#pragma unroll
    for (int i = 0; i < 4; ++i) {
      const int r = r0 + i * 32;
      gload_lds16(A + aoff + (size_t)r * 2048 + kt + c0s, &As[r][c0l]);
      gload_lds16(BT + (size_t)r * 2048 + kb + kt + c0s, &Bs[r][c0l]);
    }
    __syncthreads();
#pragma unroll
    for (int kk = 0; kk < 2; ++kk) {
      bf16x8 af[4], bfr[4];
#pragma unroll
      for (int i = 0; i < 4; ++i) {
        const int row = wr + i * 16 + lr;
        af[i] = *(const bf16x8*)&As[row][(((kk << 2) | lq) ^ (row & 7)) << 3];
      }
#pragma unroll
      for (int j = 0; j < 4; ++j) {
        const int row = wc + j * 16 + lr;
        bfr[j] = *(const bf16x8*)&Bs[row][(((kk << 2) | lq) ^ (row & 7)) << 3];
      }
#pragma unroll
      for (int i = 0; i < 4; ++i)
#pragma unroll
        for (int j = 0; j < 4; ++j)
          acc[i][j] = __builtin_amdgcn_mfma_f32_16x16x32_bf16(af[i], bfr[j], acc[i][j], 0, 0, 0);
    }
  }

  float* __restrict__ Pc = P + (size_t)ch * 196608;   // 2048*96
  const int lg4 = lq * 4;
#pragma unroll
  for (int i = 0; i < 4; ++i) {
    const int grow0 = bx * 128 + wr + i * 16 + lg4;
#pragma unroll
    for (int j = 0; j < 4; ++j) {
      const int gcol = wc + j * 16 + lr;
      if (gcol < 96) {
#pragma unroll
        for (int r = 0; r < 4; ++r)
          Pc[(size_t)(grow0 + r) * 96 + gcol] = acc[i][j][r];
      }
    }
  }
}

// merge 16 x_proj partials -> dtbf bf16 [r][64] + compact dbc32 f32 [r][32]
// grid 768 blocks x 256 thr over 2048*96 elements.
__global__ __launch_bounds__(256)
void merge_x(const float* __restrict__ P, float* __restrict__ dbc32,
             u16* __restrict__ dtbf) {
  const int idx = blockIdx.x * 256 + threadIdx.x;   // 196608
  float s = 0.f;
#pragma unroll
  for (int ch = 0; ch < 16; ++ch) s += P[(size_t)ch * 196608 + idx];
  const int r = idx / 96, c = idx - r * 96;
  if (c < 64) dtbf[r * 64 + c] = f2bf(s);
  else        dbc32[r * 32 + (c - 64)] = s;
}

// ---------------------------------------------------------------------------
// out_proj split-K 4: A=ybf[2048,2048], BT=WoT[1024,2048] (ld 2048).
// grid (16, 32): bx = row-tile, y&7 = N-tile, y>>3 = K-quarter of 512.
// ---------------------------------------------------------------------------
__global__ __launch_bounds__(256)
void outproj_split(const u16* __restrict__ A, const u16* __restrict__ BT,
                   float* __restrict__ P) {
  __shared__ u16 As[128][64];
  __shared__ u16 Bs[128][64];
  const int t = threadIdx.x;
  const int l = t & 63;
  const int w = t >> 6;
  const int wr = (w >> 1) * 64;
  const int wc = (w & 1) * 64;
  const int bx = blockIdx.x;
  const int byn = blockIdx.y & 7;
  const int ch = blockIdx.y >> 3;      // 0..3
  const int kb = ch * 512;

  const size_t aoff = (size_t)bx * 128 * 2048 + kb;
  const size_t boff = (size_t)byn * 128 * 2048 + kb;
  const int r0 = t >> 3;
  const int c0s = (((t & 7) ^ (r0 & 7)) << 3);
  const int c0l = (t & 7) << 3;
  const int lr = l & 15;
  const int lq = l >> 4;

  f32x4 acc[4][4];
#pragma unroll
  for (int i = 0; i < 4; ++i)
#pragma unroll
    for (int j = 0; j < 4; ++j) acc[i][j] = (f32x4){0.f, 0.f, 0.f, 0.f};

  for (int kt = 0; kt < 512; kt += 64) {
    __syncthreads();
#pragma unroll
    for (int i = 0; i < 4; ++i) {
      const int r = r0 + i * 32;
      gload_lds16(A + aoff + (size_t)r * 2048 + kt + c0s, &As[r][c0l]);
      gload_lds16(BT + boff + (size_t)r * 2048 + kt + c0s, &Bs[r][c0l]);
    }
    __syncthreads();
#pragma unroll
    for (int kk = 0; kk < 2; ++kk) {
      bf16x8 af[4], bfr[4];
#pragma unroll
      for (int i = 0; i < 4; ++i) {
        const int row = wr + i * 16 + lr;
        af[i] = *(const bf16x8*)&As[row][(((kk << 2) | lq) ^ (row & 7)) << 3];
      }
#pragma unroll
      for (int j = 0; j < 4; ++j) {
        const int row = wc + j * 16 + lr;
        bfr[j] = *(const bf16x8*)&Bs[row][(((kk << 2) | lq) ^ (row & 7)) << 3];
      }
#pragma unroll
      for (int i = 0; i < 4; ++i)
#pragma unroll
        for (int j = 0; j < 4; ++j)
          acc[i][j] = __builtin_amdgcn_mfma_f32_16x16x32_bf16(af[i], bfr[j], acc[i][j], 0, 0, 0);
    }
  }

  float* __restrict__ Pc = P + (size_t)ch * 2097152;
  const int lg4 = lq * 4;
#pragma unroll
  for (int i = 0; i < 4; ++i) {
    const int grow0 = bx * 128 + wr + i * 16 + lg4;
#pragma unroll
    for (int j = 0; j < 4; ++j) {
      const int gcol = byn * 128 + wc + j * 16 + lr;
#pragma unroll
      for (int r = 0; r < 4; ++r)
        Pc[(size_t)(grow0 + r) * 1024 + gcol] = acc[i][j][r];
    }
  }
}

// layer-1 merge: xbf = bf16(p0+p1+p2+p3)
__global__ __launch_bounds__(256)
void merge_o1(const float* __restrict__ P, u16* __restrict__ xbf) {
  const int i4 = (blockIdx.x * 256 + threadIdx.x) * 4;   // 2048 blocks
  float4 v = *(const float4*)(P + i4);
#pragma unroll
  for (int ch = 1; ch < 4; ++ch) {
    const float4 b = *(const float4*)(P + (size_t)ch * 2097152 + i4);
    v.x += b.x; v.y += b.y; v.z += b.z; v.w += b.w;
  }
  u16x4 o = { f2bf(v.x), f2bf(v.y), f2bf(v.z), f2bf(v.w) };
  *(u16x4*)(xbf + i4) = o;
}

// layer-2 merge + final LayerNorm fused: xlnbf = bf16(LN(sum of 4 partials))
__global__ __launch_bounds__(256)
void merge_o2_ln(const float* __restrict__ P, const float* __restrict__ g,
                 const float* __restrict__ bta, u16* __restrict__ out) {
  __shared__ float red1[4], red2[4];
  const int r = blockIdx.x;
  const int tid = threadIdx.x;
  const int lane = tid & 63, wid = tid >> 6;
  const int c4 = tid * 4;
  float4 v = *(const float4*)(P + (size_t)r * 1024 + c4);
#pragma unroll
  for (int ch = 1; ch < 4; ++ch) {
    const float4 b = *(const float4*)(P + (size_t)ch * 2097152 + (size_t)r * 1024 + c4);
    v.x += b.x; v.y += b.y; v.z += b.z; v.w += b.w;
  }
  float s = v.x + v.y + v.z + v.w;
#pragma unroll
  for (int m = 1; m < 64; m <<= 1) s += __shfl_xor(s, m, 64);
  if (lane == 0) red1[wid] = s;
  __syncthreads();
  const float mu = (red1[0] + red1[1] + red1[2] + red1[3]) * (1.f / 1024.f);
  const float d0 = v.x - mu, d1 = v.y - mu, d2 = v.z - mu, d3 = v.w - mu;
  float q = d0 * d0 + d1 * d1 + d2 * d2 + d3 * d3;
#pragma unroll
  for (int m = 1; m < 64; m <<= 1) q += __shfl_xor(q, m, 64);
  if (lane == 0) red2[wid] = q;
  __syncthreads();
  const float rs = rsqrtf((red2[0] + red2[1] + red2[2] + red2[3]) * (1.f / 1024.f) + 1e-5f);
  const float4 gv = *(const float4*)(g + c4);
  const float4 bv = *(const float4*)(bta + c4);
  u16x4 o = { f2bf(d0 * rs * gv.x + bv.x), f2bf(d1 * rs * gv.y + bv.y),
              f2bf(d2 * rs * gv.z + bv.z), f2bf(d3 * rs * gv.w + bv.w) };
  *(u16x4*)(out + (size_t)r * 1024 + c4) = o;
}

// ---------------------------------------------------------------------------
// mega prep batch: 64x64 tiles; 256B-contiguous NT reads, u16x8 stores.
// tx<0: embed gather (lt = row).
// ---------------------------------------------------------------------------
struct TBatch {
  const float* src[10];
  u16* dst[10];
  int K[10], N[10], tx[10];
  int start[11];
  int njobs;
  const int* ids;
};

__global__ __launch_bounds__(256)
void transpose_batch(TBatch tb) {
  const int tile = blockIdx.x;
  int j = 0;
  while (j + 1 < tb.njobs && tile >= tb.start[j + 1]) ++j;
  const int lt = tile - tb.start[j];

  if (tb.tx[j] < 0) {   // embed gather: row lt, 1024 cols via float4
    const int c = threadIdx.x * 4;
    const int id = tb.ids[lt];
    const float4 v = *(const float4*)(tb.src[j] + (size_t)id * 1024 + c);
    u16x4 o = { f2bf(v.x), f2bf(v.y), f2bf(v.z), f2bf(v.w) };
    *(u16x4*)(tb.dst[j] + (size_t)lt * 1024 + c) = o;
    return;
  }

  const int K = tb.K[j];
  const int N = tb.N[j];
  const int kb = (lt % tb.tx[j]) * 64;
  const int nb = (lt / tb.tx[j]) * 64;
  const float* __restrict__ in = tb.src[j];
  u16* __restrict__ out = tb.dst[j];

  __shared__ float ts[64][65];
  const int rr = threadIdx.x >> 4;        // 0..15
  const int cc = (threadIdx.x & 15) * 4;  // 0..60
  const int gn = nb + cc;
#pragma unroll
  for (int s = 0; s < 4; ++s) {
    const int k = kb + s * 16 + rr;
    f32x4 v = { 0.f, 0.f, 0.f, 0.f };
    if (gn < N) v = __builtin_nontemporal_load((const f32x4*)(in + (size_t)k * N + gn));
    ts[s * 16 + rr][cc + 0] = v[0];
    ts[s * 16 + rr][cc + 1] = v[1];
    ts[s * 16 + rr][cc + 2] = v[2];
    ts[s * 16 + rr][cc + 3] = v[3];
  }
  __syncthreads();
  const int k8 = (threadIdx.x & 7) * 8;
#pragma unroll
  for (int s = 0; s < 2; ++s) {
    const int nl = (threadIdx.x >> 3) + s * 32;   // 0..63
    u16x8 o;
#pragma unroll
    for (int i = 0; i < 8; ++i) o[i] = f2bf(ts[k8 + i][nl]);
    *(u16x8*)(out + (size_t)(nb + nl) * K + kb + k8) = o;
  }
}

// u = silu(causal_conv(xin) + cb) -> bf16.  xz is bf16. 4 ch/thread.
__global__ __launch_bounds__(256)
void conv_silu4(const u16* __restrict__ xzb, const float* __restrict__ cw,
                const float* __restrict__ cb, u16* __restrict__ ubf) {
  const int i4 = (blockIdx.x * 256 + threadIdx.x) * 4;   // grid 4096
  const int d = i4 & 2047;
  const int r = i4 >> 11;
  const int t = r & 1023;
  float4 acc = *(const float4*)(cb + d);
  const float4 w0 = *(const float4*)(cw + (d + 0) * 4);
  const float4 w1 = *(const float4*)(cw + (d + 1) * 4);
  const float4 w2 = *(const float4*)(cw + (d + 2) * 4);
  const float4 w3 = *(const float4*)(cw + (d + 3) * 4);
#pragma unroll
  for (int k = 0; k < 4; ++k) {
    const int tt = t - 3 + k;
    if (tt >= 0) {
      const u16x4 x4 = *(const u16x4*)(xzb + (size_t)(r - 3 + k) * 4096 + d);
      acc.x = fmaf(bf2f(x4[0]), ((const float*)&w0)[k], acc.x);
      acc.y = fmaf(bf2f(x4[1]), ((const float*)&w1)[k], acc.y);
      acc.z = fmaf(bf2f(x4[2]), ((const float*)&w2)[k], acc.z);
      acc.w = fmaf(bf2f(x4[3]), ((const float*)&w3)[k], acc.w);
    }
  }
  u16x4 o = { f2bf(acc.x / (1.f + __expf(-acc.x))), f2bf(acc.y / (1.f + __expf(-acc.y))),
              f2bf(acc.z / (1.f + __expf(-acc.z))), f2bf(acc.w / (1.f + __expf(-acc.w))) };
  *(u16x4*)(ubf + i4) = o;
}

// ---------------------------------------------------------------------------
// selective scan, n-in-registers; delta/u/z read as bf16 (coalesced 2B/lane).
// 32 chunks x 32 steps; grid = 2b x 8dt x 32ch = 512 blocks (2 blocks/CU).
// dbc32 compact layout [r][32]: B = cols 0-15, C = cols 16-31.
// ---------------------------------------------------------------------------
__global__ __launch_bounds__(256)
void scan_pass1(const u16* __restrict__ deltab, const u16* __restrict__ ub,
                const float* __restrict__ dbc32, const float* __restrict__ A_log,
                float* __restrict__ Pb, float* __restrict__ Qb) {
  const int blk = blockIdx.x;
  const int ch = blk & 31;
  if (ch == 31) return;          // last chunk's (P,Q) never consumed
  const int dt = (blk >> 5) & 7;
  const int b = blk >> 8;
  const int d = dt * 256 + threadIdx.x;

  float Ac[16], h[16], P[16];
#pragma unroll
  for (int n = 0; n < 16; ++n) {
    Ac[n] = -expf(A_log[d * 16 + n]) * 1.44269504f;
    h[n] = 0.f;
    P[n] = 1.f;
  }
  const int r0 = b * 1024 + ch * 32;
  for (int j = 0; j < 32; ++j) {
    const size_t r = r0 + j;
    const float dlt = bf2f(deltab[r * 2048 + d]);
    const float uu = bf2f(ub[r * 2048 + d]);
    const float du = dlt * uu;
    const float4 B0 = *(const float4*)(dbc32 + r * 32 + 0);
    const float4 B1 = *(const float4*)(dbc32 + r * 32 + 4);
    const float4 B2 = *(const float4*)(dbc32 + r * 32 + 8);
    const float4 B3 = *(const float4*)(dbc32 + r * 32 + 12);
    const float Bv[16] = { B0.x, B0.y, B0.z, B0.w, B1.x, B1.y, B1.z, B1.w,
                           B2.x, B2.y, B2.z, B2.w, B3.x, B3.y, B3.z, B3.w };
#pragma unroll
    for (int n = 0; n < 16; ++n) {
      const float da = exp2f(dlt * Ac[n]);
      P[n] *= da;
      h[n] = fmaf(da, h[n], du * Bv[n]);
    }
  }
  const size_t o = ((size_t)ch * 4096 + b * 2048 + d) * 16;
#pragma unroll
  for (int n = 0; n < 16; ++n) { Pb[o + n] = P[n]; Qb[o + n] = h[n]; }
}

// fold chunk (P,Q) into per-chunk entry states: Hp[ch] = state entering ch.
// 65536 threads, fully coalesced; same fold order as before.
__global__ __launch_bounds__(256)
void scan_prefix(const float* __restrict__ Pb, const float* __restrict__ Qb,
                 float* __restrict__ Hp) {
  const int tid = blockIdx.x * 256 + threadIdx.x;   // 65536
  float h = 0.f;
  Hp[tid] = 0.f;
  for (int ch = 0; ch < 31; ++ch) {
    const size_t o = (size_t)ch * 65536 + tid;
    h = fmaf(Pb[o], h, Qb[o]);
    Hp[o + 65536] = h;
  }
}

__global__ __launch_bounds__(256)
void scan_pass2(const u16* __restrict__ deltab, const u16* __restrict__ ub,
                const float* __restrict__ dbc32, const u16* __restrict__ xzb,
                const float* __restrict__ A_log, const float* __restrict__ Dp,
                const float* __restrict__ Hp, u16* __restrict__ ybf) {
  const int blk = blockIdx.x;
  const int ch = blk & 31;
  const int dt = (blk >> 5) & 7;
  const int b = blk >> 8;
  const int d = dt * 256 + threadIdx.x;

  float Ac[16], h[16];
  const size_t ho = ((size_t)ch * 4096 + b * 2048 + d) * 16;
#pragma unroll
  for (int n = 0; n < 16; ++n) {
    Ac[n] = -expf(A_log[d * 16 + n]) * 1.44269504f;
    h[n] = Hp[ho + n];
  }
  const float Dd = Dp[d];

  const int r0 = b * 1024 + ch * 32;
  for (int j = 0; j < 32; ++j) {
    const size_t r = r0 + j;
    const float dlt = bf2f(deltab[r * 2048 + d]);
    const float uu = bf2f(ub[r * 2048 + d]);
    const float zz = bf2f(xzb[r * 4096 + 2048 + d]);
    const float du = dlt * uu;
    const float4 B0 = *(const float4*)(dbc32 + r * 32 + 0);
    const float4 B1 = *(const float4*)(dbc32 + r * 32 + 4);
    const float4 B2 = *(const float4*)(dbc32 + r * 32 + 8);
    const float4 B3 = *(const float4*)(dbc32 + r * 32 + 12);
    const float4 C0 = *(const float4*)(dbc32 + r * 32 + 16);
    const float4 C1 = *(const float4*)(dbc32 + r * 32 + 20);
    const float4 C2 = *(const float4*)(dbc32 + r * 32 + 24);
    const float4 C3 = *(const float4*)(dbc32 + r * 32 + 28);
    const float Bv[16] = { B0.x, B0.y, B0.z, B0.w, B1.x, B1.y, B1.z, B1.w,
                           B2.x, B2.y, B2.z, B2.w, B3.x, B3.y, B3.z, B3.w };
    const float Cv[16] = { C0.x, C0.y, C0.z, C0.w, C1.x, C1.y, C1.z, C1.w,
                           C2.x, C2.y, C2.z, C2.w, C3.x, C3.y, C3.z, C3.w };
    float p0 = 0.f, p1 = 0.f, p2 = 0.f, p3 = 0.f;
#pragma unroll
    for (int n = 0; n < 16; n += 4) {
      float da;
      da = exp2f(dlt * Ac[n + 0]); h[n + 0] = fmaf(da, h[n + 0], du * Bv[n + 0]); p0 = fmaf(h[n + 0], Cv[n + 0], p0);
      da = exp2f(dlt * Ac[n + 1]); h[n + 1] = fmaf(da, h[n + 1], du * Bv[n + 1]); p1 = fmaf(h[n + 1], Cv[n + 1], p1);
      da = exp2f(dlt * Ac[n + 2]); h[n + 2] = fmaf(da, h[n + 2], du * Bv[n + 2]); p2 = fmaf(h[n + 2], Cv[n + 2], p2);
      da = exp2f(dlt * Ac[n + 3]); h[n + 3] = fmaf(da, h[n + 3], du * Bv[n + 3]); p3 = fmaf(h[n + 3], Cv[n + 3], p3);
    }
    const float p = (p0 + p1) + (p2 + p3);
    const float yv = (p + uu * Dd) * (zz / (1.f + __expf(-zz)));
    ybf[r * 2048 + d] = f2bf(yv);
  }
}

// ---------------------------------------------------------------------------
extern "C" void kernel_launch(void* const* d_in, const int* in_sizes, int n_in,
                              void* d_out, int out_size, void* d_ws, size_t ws_size,
                              hipStream_t stream) {
  (void)in_sizes; (void)n_in; (void)out_size; (void)ws_size;
  const int*   ids      = (const int*)d_in[0];
  const float* embed    = (const float*)d_in[1];
  const float* in_proj  = (const float*)d_in[2];
  const float* conv_w   = (const float*)d_in[3];
  const float* conv_b   = (const float*)d_in[4];
  const float* x_proj   = (const float*)d_in[5];
  const float* dt_w     = (const float*)d_in[6];
  const float* dt_b     = (const float*)d_in[7];
  const float* A_log    = (const float*)d_in[8];
  const float* Dp       = (const float*)d_in[9];
  const float* out_proj = (const float*)d_in[10];
  const float* ln_g     = (const float*)d_in[11];
  const float* ln_bta   = (const float*)d_in[12];
  const float* head     = (const float*)d_in[13];

  // f32 scratch inside d_out (all consumed before head GEMM overwrites)
  float* fout  = (float*)d_out;
  float* dbc32 = fout + 16777216;   // 65,536
  float* Pb    = fout + 17039360;   // 2,097,152
  float* Qb    = fout + 19136512;   // 2,097,152
  float* Hp    = fout + 21233664;   // 2,097,152
  float* xpp   = fout + 23330816;   // 16 * 196,608 = 3,145,728
  float* opp   = fout + 26476544;   // 4 * 2,097,152 = 8,388,608 (ends 34,865,152)

  // bf16 scratch in the dead tail of d_out (dead before head GEMM writes)
  u16* tail = (u16*)(fout + 35000000);
  u16* WiT[2]  = { tail,                tail + 4194304 };
  u16* WxT[2]  = { tail + 8388608,      tail + 8650752 };
  u16* WdtT[2] = { tail + 8912896,      tail + 9043968 };
  u16* WoT[2]  = { tail + 9175040,      tail + 11272192 };
  u16* dbf     = tail + 13369344;      // 4,194,304 u16 (bf16 delta)
  u16* xzb     = tail + 17563648;      // 8,388,608 u16 (ends 25,952,256 u16)

  // bf16 scratch in d_ws
  char* wp = (char*)d_ws;
  u16* headT = (u16*)wp; wp += (size_t)32000 * 1024 * 2;
  u16* xbf   = (u16*)wp; wp += (size_t)2048 * 1024 * 2;
  u16* ubf   = (u16*)wp; wp += (size_t)2048 * 2048 * 2;
  u16* dtbf  = (u16*)wp; wp += (size_t)2048 * 64 * 2;
  u16* ybf   = (u16*)wp; wp += (size_t)2048 * 2048 * 2;
  u16* xlnbf = (u16*)wp; wp += (size_t)2048 * 1024 * 2;

  const dim3 tb(256);
  const dim3 tb5(512);

  // ---- one mega prep launch: head + all layer weights + embed gather ----
  TBatch t{};
  int nj = 0, acc = 0;
  t.ids = ids;
  t.src[nj] = head; t.dst[nj] = headT;
  t.K[nj] = 1024; t.N[nj] = 32000; t.tx[nj] = 16;
  t.start[nj] = acc; acc += 16 * 500; ++nj;
  for (int i = 0; i < 2; ++i) {
    t.src[nj] = in_proj + (size_t)i * 1024 * 4096; t.dst[nj] = WiT[i];
    t.K[nj] = 1024; t.N[nj] = 4096; t.tx[nj] = 16;
    t.start[nj] = acc; acc += 16 * 64; ++nj;
    t.src[nj] = x_proj + (size_t)i * 2048 * 96; t.dst[nj] = WxT[i];
    t.K[nj] = 2048; t.N[nj] = 96; t.tx[nj] = 32;
    t.start[nj] = acc; acc += 32 * 2; ++nj;
    t.src[nj] = dt_w + (size_t)i * 64 * 2048; t.dst[nj] = WdtT[i];
    t.K[nj] = 64; t.N[nj] = 2048; t.tx[nj] = 1;
    t.start[nj] = acc; acc += 1 * 32; ++nj;
    t.src[nj] = out_proj + (size_t)i * 2048 * 1024; t.dst[nj] = WoT[i];
    t.K[nj] = 2048; t.N[nj] = 1024; t.tx[nj] = 32;
    t.start[nj] = acc; acc += 32 * 16; ++nj;
  }
  t.src[nj] = embed; t.dst[nj] = xbf;
  t.K[nj] = 0; t.N[nj] = 0; t.tx[nj] = -1;
  t.start[nj] = acc; acc += 2048; ++nj;
  t.start[nj] = acc;
  t.njobs = nj;
  transpose_batch<<<acc, tb, 0, stream>>>(t);

  for (int i = 0; i < 2; ++i) {
    gemm_bt<2><<<dim3(16, 32), tb, 0, stream>>>(xbf, WiT[i], nullptr, xzb, nullptr, 2048, 4096, 1024);
    conv_silu4<<<4096, tb, 0, stream>>>(xzb, conv_w + i * 2048 * 4, conv_b + i * 2048, ubf);
    xproj_split<<<dim3(16, 16), tb, 0, stream>>>(ubf, WxT[i], xpp);
    merge_x<<<768, tb, 0, stream>>>(xpp, dbc32, dtbf);
    gemm_bt<1><<<dim3(16, 16), tb, 0, stream>>>(dtbf, WdtT[i], nullptr, dbf, dt_b + i * 2048, 2048, 2048, 64);
    scan_pass1<<<512, tb, 0, stream>>>(dbf, ubf, dbc32, A_log + i * 2048 * 16, Pb, Qb);
    scan_prefix<<<256, tb, 0, stream>>>(Pb, Qb, Hp);
    scan_pass2<<<512, tb, 0, stream>>>(dbf, ubf, dbc32, xzb, A_log + i * 2048 * 16, Dp + i * 2048, Hp, ybf);
    outproj_split<<<dim3(16, 32), tb, 0, stream>>>(ybf, WoT[i], opp);
    if (i == 0) {
      merge_o1<<<2048, tb, 0, stream>>>(opp, xbf);
    } else {
      merge_o2_ln<<<2048, tb, 0, stream>>>(opp, ln_g, ln_bta, xlnbf);
    }
  }

  gemm256<<<dim3(8, 125), tb5, 0, stream>>>(xlnbf, headT, fout, 2048, 32000, 1024);
}

// Round 18
// 517.191 us; speedup vs baseline: 1.0302x; 1.0221x over previous
//
#include <hip/hip_runtime.h>

typedef unsigned short u16;
typedef __attribute__((ext_vector_type(8))) short bf16x8;
typedef __attribute__((ext_vector_type(4))) float f32x4;
typedef __attribute__((ext_vector_type(4))) u16 u16x4;
typedef __attribute__((ext_vector_type(8))) u16 u16x8;

#define DEV static __device__ __forceinline__

DEV u16 f2bf(float f) {
  union { float f; unsigned u; } v; v.f = f;
  unsigned r = (v.u + 0x7fffu + ((v.u >> 16) & 1u)) >> 16;
  return (u16)r;
}

DEV float bf2f(u16 v) { return __int_as_float(((int)v) << 16); }

DEV void gload_lds16(const void* g, void* l) {
  __builtin_amdgcn_global_load_lds(
      (const __attribute__((address_space(1))) unsigned int*)g,
      (__attribute__((address_space(3))) unsigned int*)l, 16, 0, 0);
}

// ---------------------------------------------------------------------------
// 256x256 8-wave MFMA GEMM — m201 8-phase (HEAD GEMM only). Plain C stores.
// ---------------------------------------------------------------------------
#define STGH(buf, mat, half, P, kt) { \
    const int r_ = (half) * 128 + sr0; \
    gload_lds16((P) + (size_t)r_ * K + (kt) + scs, &lds[buf][mat][r_][sc8]); \
    gload_lds16((P) + (size_t)(r_ + 64) * K + (kt) + scs, &lds[buf][mat][r_ + 64][sc8]); }
#define LDB(buf) _Pragma("unroll") for (int n = 0; n < 4; ++n) { \
    const int row = wn * 64 + n * 16 + lr; \
    _Pragma("unroll") for (int kk = 0; kk < 2; ++kk) \
      bfr[n][kk] = *(const bf16x8*)&lds[buf][1][row][(((kk << 2) | lq) ^ (row & 7)) << 3]; }
#define LDA(buf, p) _Pragma("unroll") for (int mi = 0; mi < 2; ++mi) { \
    const int row = wm * 128 + ((p) * 2 + mi) * 16 + lr; \
    _Pragma("unroll") for (int kk = 0; kk < 2; ++kk) \
      af[mi][kk] = *(const bf16x8*)&lds[buf][0][row][(((kk << 2) | lq) ^ (row & 7)) << 3]; }
#define MM(p) __builtin_amdgcn_s_setprio(1); \
  _Pragma("unroll") for (int kk = 0; kk < 2; ++kk) \
  _Pragma("unroll") for (int mi = 0; mi < 2; ++mi) \
  _Pragma("unroll") for (int n = 0; n < 4; ++n) \
    acc[(p) * 2 + mi][n] = __builtin_amdgcn_mfma_f32_16x16x32_bf16(af[mi][kk], bfr[n][kk], acc[(p) * 2 + mi][n], 0, 0, 0); \
  __builtin_amdgcn_s_setprio(0);
#define BAR() { __builtin_amdgcn_s_barrier(); asm volatile("" ::: "memory"); }
#define WLG() { asm volatile("s_waitcnt lgkmcnt(0)" ::: "memory"); __builtin_amdgcn_sched_barrier(0); }
#define VMC(n) asm volatile("s_waitcnt vmcnt(" #n ")" ::: "memory")

__global__ __launch_bounds__(512, 1)
void gemm256(const u16* __restrict__ A, const u16* __restrict__ BT,
             float* __restrict__ C, int M, int N, int K) {
  __shared__ u16 lds[2][2][256][64];   // [buf][A=0,B=1][row][k]
  const int t = threadIdx.x;
  const int l = t & 63;
  const int w = t >> 6;
  const int wm = w >> 2;        // 0..1
  const int wn = w & 3;         // 0..3
  const int lr = l & 15, lq = l >> 4;

  const int gn = N >> 8;
  const int nwg = gn << 3;
  const int orig = blockIdx.y * 8 + blockIdx.x;
  const int q = nwg >> 3;
  const int swz = (orig & 7) * q + (orig >> 3);
  const int bx = swz & 7;
  const int by = swz >> 3;

  const u16* Ap = A + (size_t)bx * 256 * K;
  const u16* Bp = BT + (size_t)by * 256 * K;
  const int sr0 = t >> 3;
  const int sc8 = (t & 7) << 3;
  const int scs = (((t & 7) ^ (sr0 & 7)) << 3);

  f32x4 acc[8][4];
#pragma unroll
  for (int m = 0; m < 8; ++m)
#pragma unroll
    for (int n = 0; n < 4; ++n) acc[m][n] = (f32x4){0.f, 0.f, 0.f, 0.f};

  const int NI = K >> 7;
  STGH(0, 1, 0, Bp, 0) STGH(0, 1, 1, Bp, 0)
  STGH(0, 0, 0, Ap, 0) STGH(0, 0, 1, Ap, 0)
  STGH(1, 1, 0, Bp, 64) STGH(1, 1, 1, Bp, 64)
  VMC(4);
  BAR();

  for (int ip = 0; ip < NI; ++ip) {
    const int k0 = ip << 7;
    const bool m2 = (k0 + 128) < K;
    const bool m3 = (k0 + 192) < K;
    bf16x8 bfr[4][2], af[2][2];
    LDB(0) LDA(0, 0)
    STGH(1, 0, 0, Ap, k0 + 64)
    BAR(); WLG(); MM(0) BAR();
    LDA(0, 1)
    STGH(1, 0, 1, Ap, k0 + 64)
    BAR(); WLG(); MM(1) BAR();
    LDA(0, 2)
    if (m2) STGH(0, 1, 0, Bp, k0 + 128)
    BAR(); WLG(); MM(2) BAR();
    LDA(0, 3)
    if (m2) STGH(0, 1, 1, Bp, k0 + 128)
    BAR(); WLG(); MM(3)
    if (m2) { VMC(4); } else { VMC(0); }
    BAR();
    LDB(1) LDA(1, 0)
    if (m2) STGH(0, 0, 0, Ap, k0 + 128)
    BAR(); WLG(); MM(0) BAR();
    LDA(1, 1)
    if (m2) STGH(0, 0, 1, Ap, k0 + 128)
    BAR(); WLG(); MM(1) BAR();
    LDA(1, 2)
    if (m3) STGH(1, 1, 0, Bp, k0 + 192)
    BAR(); WLG(); MM(2) BAR();
    LDA(1, 3)
    if (m3) STGH(1, 1, 1, Bp, k0 + 192)
    BAR(); WLG(); MM(3)
    if (m3) { VMC(4); } else { VMC(0); }
    BAR();
  }

  const int lg4 = lq * 4;
#pragma unroll
  for (int m = 0; m < 8; ++m) {
    const int grow0 = bx * 256 + wm * 128 + m * 16 + lg4;
#pragma unroll
    for (int n = 0; n < 4; ++n) {
      const int gcol = by * 256 + wn * 64 + n * 16 + lr;
#pragma unroll
      for (int r = 0; r < 4; ++r) {
        const size_t idx = (size_t)(grow0 + r) * N + gcol;
        C[idx] = acc[m][n][r];
      }
    }
  }
}
#undef STGH
#undef LDB
#undef LDA
#undef MM
#undef BAR
#undef WLG
#undef VMC

// ---------------------------------------------------------------------------
// 128x128 BK=64 GEMM.  EPI: 0 = f32 C; 1 = +bias, softplus, bf16 Cbf;
// 2 = plain bf16 Cbf.  gridDim.x MUST be 16; nwg % 8 == 0.
// ---------------------------------------------------------------------------
template<int EPI>
__global__ __launch_bounds__(256)
void gemm_bt(const u16* __restrict__ A, const u16* __restrict__ BT,
             float* __restrict__ C, u16* __restrict__ Cbf,
             const float* __restrict__ bias, int M, int N, int K) {
  __shared__ u16 As[128][64];
  __shared__ u16 Bs[128][64];
  const int t = threadIdx.x;
  const int l = t & 63;
  const int w = t >> 6;
  const int wr = (w >> 1) * 64;
  const int wc = (w & 1) * 64;

  const int nwg = gridDim.x * gridDim.y;
  const int orig = blockIdx.y * gridDim.x + blockIdx.x;
  const int swz = (orig & 7) * (nwg >> 3) + (orig >> 3);
  const int bx = swz & 15;
  const int by = swz >> 4;

  const size_t aoff = (size_t)bx * 128 * K;
  const size_t boff = (size_t)by * 128 * K;
  const int r0 = t >> 3;
  const int c0s = (((t & 7) ^ (r0 & 7)) << 3);
  const int c0l = (t & 7) << 3;
  const int lr = l & 15;
  const int lq = l >> 4;

  f32x4 acc[4][4];
#pragma unroll
  for (int i = 0; i < 4; ++i)
#pragma unroll
    for (int j = 0; j < 4; ++j) acc[i][j] = (f32x4){0.f, 0.f, 0.f, 0.f};

  for (int kt = 0; kt < K; kt += 64) {
    __syncthreads();
#pragma unroll
    for (int i = 0; i < 4; ++i) {
      const int r = r0 + i * 32;
      gload_lds16(A + aoff + (size_t)r * K + kt + c0s, &As[r][c0l]);
      gload_lds16(BT + boff + (size_t)r * K + kt + c0s, &Bs[r][c0l]);
    }
    __syncthreads();
#pragma unroll
    for (int kk = 0; kk < 2; ++kk) {
      bf16x8 af[4], bfr[4];
#pragma unroll
      for (int i = 0; i < 4; ++i) {
        const int row = wr + i * 16 + lr;
        af[i] = *(const bf16x8*)&As[row][(((kk << 2) | lq) ^ (row & 7)) << 3];
      }
#pragma unroll
      for (int j = 0; j < 4; ++j) {
        const int row = wc + j * 16 + lr;
        bfr[j] = *(const bf16x8*)&Bs[row][(((kk << 2) | lq) ^ (row & 7)) << 3];
      }
#pragma unroll
      for (int i = 0; i < 4; ++i)
#pragma unroll
        for (int j = 0; j < 4; ++j)
          acc[i][j] = __builtin_amdgcn_mfma_f32_16x16x32_bf16(af[i], bfr[j], acc[i][j], 0, 0, 0);
    }
  }

  const int lg4 = lq * 4;
#pragma unroll
  for (int i = 0; i < 4; ++i) {
    const int grow0 = bx * 128 + wr + i * 16 + lg4;
#pragma unroll
    for (int j = 0; j < 4; ++j) {
      const int gcol = by * 128 + wc + j * 16 + lr;
      float bv = 0.f;
      if (EPI == 1) bv = bias[gcol];
#pragma unroll
      for (int r = 0; r < 4; ++r) {
        float v = acc[i][j][r];
        if (EPI == 0) {
          C[(size_t)(grow0 + r) * N + gcol] = v;
        } else if (EPI == 1) {
          v += bv;
          v = fmaxf(v, 0.f) + log1pf(expf(-fabsf(v)));   // stable softplus
          Cbf[(size_t)(grow0 + r) * N + gcol] = f2bf(v);
        } else {
          Cbf[(size_t)(grow0 + r) * N + gcol] = f2bf(v);
        }
      }
    }
  }
}

// ---------------------------------------------------------------------------
// x_proj split-K 16: A=ubf[2048,2048], BT=WxT[128,2048] (both ld 2048).
// grid (16, 16): bx = row-tile, ch = K-chunk of 128. Partials to P[r][96]
// (padding cols 96-127 are zeros — not written).
// ---------------------------------------------------------------------------
__global__ __launch_bounds__(256)
void xproj_split(const u16* __restrict__ A, const u16* __restrict__ BT,
                 float* __restrict__ P) {
  __shared__ u16 As[128][64];
  __shared__ u16 Bs[128][64];
  const int t = threadIdx.x;
  const int l = t & 63;
  const int w = t >> 6;
  const int wr = (w >> 1) * 64;
  const int wc = (w & 1) * 64;
  const int bx = blockIdx.x;
  const int ch = blockIdx.y;
  const int kb = ch * 128;

  const size_t aoff = (size_t)bx * 128 * 2048 + kb;
  const int r0 = t >> 3;
  const int c0s = (((t & 7) ^ (r0 & 7)) << 3);
  const int c0l = (t & 7) << 3;
  const int lr = l & 15;
  const int lq = l >> 4;

  f32x4 acc[4][4];
#pragma unroll
  for (int i = 0; i < 4; ++i)
#pragma unroll
    for (int j = 0; j < 4; ++j) acc[i][j] = (f32x4){0.f, 0.f, 0.f, 0.f};

  for (int kt = 0; kt < 128; kt += 64) {
    __syncthreads();
#pragma unroll
    for (int i = 0; i < 4; ++i) {
      const int r = r0 + i * 32;
      gload_lds16(A + aoff + (size_t)r * 2048 + kt + c0s, &As[r][c0l]);
      gload_lds16(BT + (size_t)r * 2048 + kb + kt + c0s, &Bs[r][c0l]);
    }
    __syncthreads();
#pragma unroll
    for (int kk = 0; kk < 2; ++kk) {
      bf16x8 af[4], bfr[4];
#pragma unroll
      for (int i = 0; i < 4; ++i) {
        const int row = wr + i * 16 + lr;
        af[i] = *(const bf16x8*)&As[row][(((kk << 2) | lq) ^ (row & 7)) << 3];
      }
#pragma unroll
      for (int j = 0; j < 4; ++j) {
        const int row = wc + j * 16 + lr;
        bfr[j] = *(const bf16x8*)&Bs[row][(((kk << 2) | lq) ^ (row & 7)) << 3];
      }
#pragma unroll
      for (int i = 0; i < 4; ++i)
#pragma unroll
        for (int j = 0; j < 4; ++j)
          acc[i][j] = __builtin_amdgcn_mfma_f32_16x16x32_bf16(af[i], bfr[j], acc[i][j], 0, 0, 0);
    }
  }

  float* __restrict__ Pc = P + (size_t)ch * 196608;   // 2048*96
  const int lg4 = lq * 4;
#pragma unroll
  for (int i = 0; i < 4; ++i) {
    const int grow0 = bx * 128 + wr + i * 16 + lg4;
#pragma unroll
    for (int j = 0; j < 4; ++j) {
      const int gcol = wc + j * 16 + lr;
      if (gcol < 96) {
#pragma unroll
        for (int r = 0; r < 4; ++r)
          Pc[(size_t)(grow0 + r) * 96 + gcol] = acc[i][j][r];
      }
    }
  }
}

// merge 16 x_proj partials -> dtbf bf16 [r][64] + compact dbc32 f32 [r][32]
__global__ __launch_bounds__(256)
void merge_x(const float* __restrict__ P, float* __restrict__ dbc32,
             u16* __restrict__ dtbf) {
  const int idx = blockIdx.x * 256 + threadIdx.x;   // 196608
  float s = 0.f;
#pragma unroll
  for (int ch = 0; ch < 16; ++ch) s += P[(size_t)ch * 196608 + idx];
  const int r = idx / 96, c = idx - r * 96;
  if (c < 64) dtbf[r * 64 + c] = f2bf(s);
  else        dbc32[r * 32 + (c - 64)] = s;
}

// ---------------------------------------------------------------------------
// out_proj split-K 4: A=ybf[2048,2048], BT=WoT[1024,2048] (ld 2048).
// grid (16, 32): bx = row-tile, y&7 = N-tile, y>>3 = K-quarter of 512.
// ---------------------------------------------------------------------------
__global__ __launch_bounds__(256)
void outproj_split(const u16* __restrict__ A, const u16* __restrict__ BT,
                   float* __restrict__ P) {
  __shared__ u16 As[128][64];
  __shared__ u16 Bs[128][64];
  const int t = threadIdx.x;
  const int l = t & 63;
  const int w = t >> 6;
  const int wr = (w >> 1) * 64;
  const int wc = (w & 1) * 64;
  const int bx = blockIdx.x;
  const int byn = blockIdx.y & 7;
  const int ch = blockIdx.y >> 3;      // 0..3
  const int kb = ch * 512;

  const size_t aoff = (size_t)bx * 128 * 2048 + kb;
  const size_t boff = (size_t)byn * 128 * 2048 + kb;
  const int r0 = t >> 3;
  const int c0s = (((t & 7) ^ (r0 & 7)) << 3);
  const int c0l = (t & 7) << 3;
  const int lr = l & 15;
  const int lq = l >> 4;

  f32x4 acc[4][4];
#pragma unroll
  for (int i = 0; i < 4; ++i)
#pragma unroll
    for (int j = 0; j < 4; ++j) acc[i][j] = (f32x4){0.f, 0.f, 0.f, 0.f};

  for (int kt = 0; kt < 512; kt += 64) {
    __syncthreads();
#pragma unroll
    for (int i = 0; i < 4; ++i) {
      const int r = r0 + i * 32;
      gload_lds16(A + aoff + (size_t)r * 2048 + kt + c0s, &As[r][c0l]);
      gload_lds16(BT + boff + (size_t)r * 2048 + kt + c0s, &Bs[r][c0l]);
    }
    __syncthreads();
#pragma unroll
    for (int kk = 0; kk < 2; ++kk) {
      bf16x8 af[4], bfr[4];
#pragma unroll
      for (int i = 0; i < 4; ++i) {
        const int row = wr + i * 16 + lr;
        af[i] = *(const bf16x8*)&As[row][(((kk << 2) | lq) ^ (row & 7)) << 3];
      }
#pragma unroll
      for (int j = 0; j < 4; ++j) {
        const int row = wc + j * 16 + lr;
        bfr[j] = *(const bf16x8*)&Bs[row][(((kk << 2) | lq) ^ (row & 7)) << 3];
      }
#pragma unroll
      for (int i = 0; i < 4; ++i)
#pragma unroll
        for (int j = 0; j < 4; ++j)
          acc[i][j] = __builtin_amdgcn_mfma_f32_16x16x32_bf16(af[i], bfr[j], acc[i][j], 0, 0, 0);
    }
  }

  float* __restrict__ Pc = P + (size_t)ch * 2097152;
  const int lg4 = lq * 4;
#pragma unroll
  for (int i = 0; i < 4; ++i) {
    const int grow0 = bx * 128 + wr + i * 16 + lg4;
#pragma unroll
    for (int j = 0; j < 4; ++j) {
      const int gcol = byn * 128 + wc + j * 16 + lr;
#pragma unroll
      for (int r = 0; r < 4; ++r)
        Pc[(size_t)(grow0 + r) * 1024 + gcol] = acc[i][j][r];
    }
  }
}

// layer-1 merge: xbf = bf16(p0+p1+p2+p3)
__global__ __launch_bounds__(256)
void merge_o1(const float* __restrict__ P, u16* __restrict__ xbf) {
  const int i4 = (blockIdx.x * 256 + threadIdx.x) * 4;   // 2048 blocks
  float4 v = *(const float4*)(P + i4);
#pragma unroll
  for (int ch = 1; ch < 4; ++ch) {
    const float4 b = *(const float4*)(P + (size_t)ch * 2097152 + i4);
    v.x += b.x; v.y += b.y; v.z += b.z; v.w += b.w;
  }
  u16x4 o = { f2bf(v.x), f2bf(v.y), f2bf(v.z), f2bf(v.w) };
  *(u16x4*)(xbf + i4) = o;
}

// layer-2 merge + final LayerNorm fused: xlnbf = bf16(LN(sum of 4 partials))
__global__ __launch_bounds__(256)
void merge_o2_ln(const float* __restrict__ P, const float* __restrict__ g,
                 const float* __restrict__ bta, u16* __restrict__ out) {
  __shared__ float red1[4], red2[4];
  const int r = blockIdx.x;
  const int tid = threadIdx.x;
  const int lane = tid & 63, wid = tid >> 6;
  const int c4 = tid * 4;
  float4 v = *(const float4*)(P + (size_t)r * 1024 + c4);
#pragma unroll
  for (int ch = 1; ch < 4; ++ch) {
    const float4 b = *(const float4*)(P + (size_t)ch * 2097152 + (size_t)r * 1024 + c4);
    v.x += b.x; v.y += b.y; v.z += b.z; v.w += b.w;
  }
  float s = v.x + v.y + v.z + v.w;
#pragma unroll
  for (int m = 1; m < 64; m <<= 1) s += __shfl_xor(s, m, 64);
  if (lane == 0) red1[wid] = s;
  __syncthreads();
  const float mu = (red1[0] + red1[1] + red1[2] + red1[3]) * (1.f / 1024.f);
  const float d0 = v.x - mu, d1 = v.y - mu, d2 = v.z - mu, d3 = v.w - mu;
  float q = d0 * d0 + d1 * d1 + d2 * d2 + d3 * d3;
#pragma unroll
  for (int m = 1; m < 64; m <<= 1) q += __shfl_xor(q, m, 64);
  if (lane == 0) red2[wid] = q;
  __syncthreads();
  const float rs = rsqrtf((red2[0] + red2[1] + red2[2] + red2[3]) * (1.f / 1024.f) + 1e-5f);
  const float4 gv = *(const float4*)(g + c4);
  const float4 bv = *(const float4*)(bta + c4);
  u16x4 o = { f2bf(d0 * rs * gv.x + bv.x), f2bf(d1 * rs * gv.y + bv.y),
              f2bf(d2 * rs * gv.z + bv.z), f2bf(d3 * rs * gv.w + bv.w) };
  *(u16x4*)(out + (size_t)r * 1024 + c4) = o;
}

// ---------------------------------------------------------------------------
// mega prep batch: 64x64 tiles; 256B-contiguous NT reads, u16x8 stores.
// tx<0: embed gather (lt = row).
// ---------------------------------------------------------------------------
struct TBatch {
  const float* src[10];
  u16* dst[10];
  int K[10], N[10], tx[10];
  int start[11];
  int njobs;
  const int* ids;
};

__global__ __launch_bounds__(256)
void transpose_batch(TBatch tb) {
  const int tile = blockIdx.x;
  int j = 0;
  while (j + 1 < tb.njobs && tile >= tb.start[j + 1]) ++j;
  const int lt = tile - tb.start[j];

  if (tb.tx[j] < 0) {   // embed gather: row lt, 1024 cols via float4
    const int c = threadIdx.x * 4;
    const int id = tb.ids[lt];
    const float4 v = *(const float4*)(tb.src[j] + (size_t)id * 1024 + c);
    u16x4 o = { f2bf(v.x), f2bf(v.y), f2bf(v.z), f2bf(v.w) };
    *(u16x4*)(tb.dst[j] + (size_t)lt * 1024 + c) = o;
    return;
  }

  const int K = tb.K[j];
  const int N = tb.N[j];
  const int kb = (lt % tb.tx[j]) * 64;
  const int nb = (lt / tb.tx[j]) * 64;
  const float* __restrict__ in = tb.src[j];
  u16* __restrict__ out = tb.dst[j];

  __shared__ float ts[64][65];
  const int rr = threadIdx.x >> 4;        // 0..15
  const int cc = (threadIdx.x & 15) * 4;  // 0..60
  const int gn = nb + cc;
#pragma unroll
  for (int s = 0; s < 4; ++s) {
    const int k = kb + s * 16 + rr;
    f32x4 v = { 0.f, 0.f, 0.f, 0.f };
    if (gn < N) v = __builtin_nontemporal_load((const f32x4*)(in + (size_t)k * N + gn));
    ts[s * 16 + rr][cc + 0] = v[0];
    ts[s * 16 + rr][cc + 1] = v[1];
    ts[s * 16 + rr][cc + 2] = v[2];
    ts[s * 16 + rr][cc + 3] = v[3];
  }
  __syncthreads();
  const int k8 = (threadIdx.x & 7) * 8;
#pragma unroll
  for (int s = 0; s < 2; ++s) {
    const int nl = (threadIdx.x >> 3) + s * 32;   // 0..63
    u16x8 o;
#pragma unroll
    for (int i = 0; i < 8; ++i) o[i] = f2bf(ts[k8 + i][nl]);
    *(u16x8*)(out + (size_t)(nb + nl) * K + kb + k8) = o;
  }
}

// u = silu(causal_conv(xin) + cb) -> bf16.  xz is bf16. 4 ch/thread.
__global__ __launch_bounds__(256)
void conv_silu4(const u16* __restrict__ xzb, const float* __restrict__ cw,
                const float* __restrict__ cb, u16* __restrict__ ubf) {
  const int i4 = (blockIdx.x * 256 + threadIdx.x) * 4;   // grid 4096
  const int d = i4 & 2047;
  const int r = i4 >> 11;
  const int t = r & 1023;
  float4 acc = *(const float4*)(cb + d);
  const float4 w0 = *(const float4*)(cw + (d + 0) * 4);
  const float4 w1 = *(const float4*)(cw + (d + 1) * 4);
  const float4 w2 = *(const float4*)(cw + (d + 2) * 4);
  const float4 w3 = *(const float4*)(cw + (d + 3) * 4);
#pragma unroll
  for (int k = 0; k < 4; ++k) {
    const int tt = t - 3 + k;
    if (tt >= 0) {
      const u16x4 x4 = *(const u16x4*)(xzb + (size_t)(r - 3 + k) * 4096 + d);
      acc.x = fmaf(bf2f(x4[0]), ((const float*)&w0)[k], acc.x);
      acc.y = fmaf(bf2f(x4[1]), ((const float*)&w1)[k], acc.y);
      acc.z = fmaf(bf2f(x4[2]), ((const float*)&w2)[k], acc.z);
      acc.w = fmaf(bf2f(x4[3]), ((const float*)&w3)[k], acc.w);
    }
  }
  u16x4 o = { f2bf(acc.x / (1.f + __expf(-acc.x))), f2bf(acc.y / (1.f + __expf(-acc.y))),
              f2bf(acc.z / (1.f + __expf(-acc.z))), f2bf(acc.w / (1.f + __expf(-acc.w))) };
  *(u16x4*)(ubf + i4) = o;
}

// ---------------------------------------------------------------------------
// selective scan, n-in-registers; delta/u/z read as bf16 (coalesced 2B/lane).
// 32 chunks x 32 steps; grid = 2b x 8dt x 32ch = 512 blocks (2 blocks/CU).
// dbc32 compact layout [r][32]: B = cols 0-15, C = cols 16-31.
// Chunk-state buffers Pb/Qb/Hp stored as bf16 (halves the carrier traffic).
// ---------------------------------------------------------------------------
__global__ __launch_bounds__(256)
void scan_pass1(const u16* __restrict__ deltab, const u16* __restrict__ ub,
                const float* __restrict__ dbc32, const float* __restrict__ A_log,
                u16* __restrict__ Pb, u16* __restrict__ Qb) {
  const int blk = blockIdx.x;
  const int ch = blk & 31;
  if (ch == 31) return;          // last chunk's (P,Q) never consumed
  const int dt = (blk >> 5) & 7;
  const int b = blk >> 8;
  const int d = dt * 256 + threadIdx.x;

  float Ac[16], h[16], P[16];
#pragma unroll
  for (int n = 0; n < 16; ++n) {
    Ac[n] = -expf(A_log[d * 16 + n]) * 1.44269504f;
    h[n] = 0.f;
    P[n] = 1.f;
  }
  const int r0 = b * 1024 + ch * 32;
  for (int j = 0; j < 32; ++j) {
    const size_t r = r0 + j;
    const float dlt = bf2f(deltab[r * 2048 + d]);
    const float uu = bf2f(ub[r * 2048 + d]);
    const float du = dlt * uu;
    const float4 B0 = *(const float4*)(dbc32 + r * 32 + 0);
    const float4 B1 = *(const float4*)(dbc32 + r * 32 + 4);
    const float4 B2 = *(const float4*)(dbc32 + r * 32 + 8);
    const float4 B3 = *(const float4*)(dbc32 + r * 32 + 12);
    const float Bv[16] = { B0.x, B0.y, B0.z, B0.w, B1.x, B1.y, B1.z, B1.w,
                           B2.x, B2.y, B2.z, B2.w, B3.x, B3.y, B3.z, B3.w };
#pragma unroll
    for (int n = 0; n < 16; ++n) {
      const float da = exp2f(dlt * Ac[n]);
      P[n] *= da;
      h[n] = fmaf(da, h[n], du * Bv[n]);
    }
  }
  const size_t o = ((size_t)ch * 4096 + b * 2048 + d) * 16;
  u16x8 p0, p1, q0, q1;
#pragma unroll
  for (int n = 0; n < 8; ++n) { p0[n] = f2bf(P[n]); p1[n] = f2bf(P[n + 8]);
                                q0[n] = f2bf(h[n]); q1[n] = f2bf(h[n + 8]); }
  *(u16x8*)(Pb + o) = p0; *(u16x8*)(Pb + o + 8) = p1;
  *(u16x8*)(Qb + o) = q0; *(u16x8*)(Qb + o + 8) = q1;
}

// fold chunk (P,Q) into per-chunk entry states: Hp[ch] = state entering ch.
// 65536 threads (one per (b,d,n) state), fully coalesced; fold order preserved.
__global__ __launch_bounds__(256)
void scan_prefix(const u16* __restrict__ Pb, const u16* __restrict__ Qb,
                 u16* __restrict__ Hp) {
  const int tid = blockIdx.x * 256 + threadIdx.x;   // 65536
  float h = 0.f;
  Hp[tid] = 0;
  for (int ch = 0; ch < 31; ++ch) {
    const size_t o = (size_t)ch * 65536 + tid;
    h = fmaf(bf2f(Pb[o]), h, bf2f(Qb[o]));
    Hp[o + 65536] = f2bf(h);
  }
}

__global__ __launch_bounds__(256)
void scan_pass2(const u16* __restrict__ deltab, const u16* __restrict__ ub,
                const float* __restrict__ dbc32, const u16* __restrict__ xzb,
                const float* __restrict__ A_log, const float* __restrict__ Dp,
                const u16* __restrict__ Hp, u16* __restrict__ ybf) {
  const int blk = blockIdx.x;
  const int ch = blk & 31;
  const int dt = (blk >> 5) & 7;
  const int b = blk >> 8;
  const int d = dt * 256 + threadIdx.x;

  float Ac[16], h[16];
  const size_t ho = ((size_t)ch * 4096 + b * 2048 + d) * 16;
#pragma unroll
  for (int n = 0; n < 16; ++n) {
    Ac[n] = -expf(A_log[d * 16 + n]) * 1.44269504f;
    h[n] = bf2f(Hp[ho + n]);
  }
  const float Dd = Dp[d];

  const int r0 = b * 1024 + ch * 32;
  for (int j = 0; j < 32; ++j) {
    const size_t r = r0 + j;
    const float dlt = bf2f(deltab[r * 2048 + d]);
    const float uu = bf2f(ub[r * 2048 + d]);
    const float zz = bf2f(xzb[r * 4096 + 2048 + d]);
    const float du = dlt * uu;
    const float4 B0 = *(const float4*)(dbc32 + r * 32 + 0);
    const float4 B1 = *(const float4*)(dbc32 + r * 32 + 4);
    const float4 B2 = *(const float4*)(dbc32 + r * 32 + 8);
    const float4 B3 = *(const float4*)(dbc32 + r * 32 + 12);
    const float4 C0 = *(const float4*)(dbc32 + r * 32 + 16);
    const float4 C1 = *(const float4*)(dbc32 + r * 32 + 20);
    const float4 C2 = *(const float4*)(dbc32 + r * 32 + 24);
    const float4 C3 = *(const float4*)(dbc32 + r * 32 + 28);
    const float Bv[16] = { B0.x, B0.y, B0.z, B0.w, B1.x, B1.y, B1.z, B1.w,
                           B2.x, B2.y, B2.z, B2.w, B3.x, B3.y, B3.z, B3.w };
    const float Cv[16] = { C0.x, C0.y, C0.z, C0.w, C1.x, C1.y, C1.z, C1.w,
                           C2.x, C2.y, C2.z, C2.w, C3.x, C3.y, C3.z, C3.w };
    float p0 = 0.f, p1 = 0.f, p2 = 0.f, p3 = 0.f;
#pragma unroll
    for (int n = 0; n < 16; n += 4) {
      float da;
      da = exp2f(dlt * Ac[n + 0]); h[n + 0] = fmaf(da, h[n + 0], du * Bv[n + 0]); p0 = fmaf(h[n + 0], Cv[n + 0], p0);
      da = exp2f(dlt * Ac[n + 1]); h[n + 1] = fmaf(da, h[n + 1], du * Bv[n + 1]); p1 = fmaf(h[n + 1], Cv[n + 1], p1);
      da = exp2f(dlt * Ac[n + 2]); h[n + 2] = fmaf(da, h[n + 2], du * Bv[n + 2]); p2 = fmaf(h[n + 2], Cv[n + 2], p2);
      da = exp2f(dlt * Ac[n + 3]); h[n + 3] = fmaf(da, h[n + 3], du * Bv[n + 3]); p3 = fmaf(h[n + 3], Cv[n + 3], p3);
    }
    const float p = (p0 + p1) + (p2 + p3);
    const float yv = (p + uu * Dd) * (zz / (1.f + __expf(-zz)));
    ybf[r * 2048 + d] = f2bf(yv);
  }
}

// ---------------------------------------------------------------------------
extern "C" void kernel_launch(void* const* d_in, const int* in_sizes, int n_in,
                              void* d_out, int out_size, void* d_ws, size_t ws_size,
                              hipStream_t stream) {
  (void)in_sizes; (void)n_in; (void)out_size; (void)ws_size;
  const int*   ids      = (const int*)d_in[0];
  const float* embed    = (const float*)d_in[1];
  const float* in_proj  = (const float*)d_in[2];
  const float* conv_w   = (const float*)d_in[3];
  const float* conv_b   = (const float*)d_in[4];
  const float* x_proj   = (const float*)d_in[5];
  const float* dt_w     = (const float*)d_in[6];
  const float* dt_b     = (const float*)d_in[7];
  const float* A_log    = (const float*)d_in[8];
  const float* Dp       = (const float*)d_in[9];
  const float* out_proj = (const float*)d_in[10];
  const float* ln_g     = (const float*)d_in[11];
  const float* ln_bta   = (const float*)d_in[12];
  const float* head     = (const float*)d_in[13];

  // f32 scratch inside d_out (all consumed before head GEMM overwrites)
  float* fout  = (float*)d_out;
  float* dbc32 = fout + 16777216;   // 65,536
  float* xpp   = fout + 17039360;   // 16 * 196,608 = 3,145,728 (ends 20,185,088)
  float* opp   = fout + 20185088;   // 4 * 2,097,152 = 8,388,608 (ends 28,573,696)

  // bf16 scratch in the dead tail of d_out (dead before head GEMM writes)
  u16* tail = (u16*)(fout + 29000000);
  u16* WiT[2]  = { tail,                tail + 4194304 };
  u16* WxT[2]  = { tail + 8388608,      tail + 8650752 };
  u16* WdtT[2] = { tail + 8912896,      tail + 9043968 };
  u16* WoT[2]  = { tail + 9175040,      tail + 11272192 };
  u16* dbf     = tail + 13369344;      // 4,194,304 u16 (bf16 delta)
  u16* xzb     = tail + 17563648;      // 8,388,608 u16
  u16* Pbh     = tail + 25952256;      // 2,097,152 u16 (bf16 chunk P)
  u16* Qbh     = tail + 28049408;      // 2,097,152 u16 (bf16 chunk Q)
  u16* Hph     = tail + 30146560;      // 2,097,152 u16 (bf16 entry state)

  // bf16 scratch in d_ws
  char* wp = (char*)d_ws;
  u16* headT = (u16*)wp; wp += (size_t)32000 * 1024 * 2;
  u16* xbf   = (u16*)wp; wp += (size_t)2048 * 1024 * 2;
  u16* ubf   = (u16*)wp; wp += (size_t)2048 * 2048 * 2;
  u16* dtbf  = (u16*)wp; wp += (size_t)2048 * 64 * 2;
  u16* ybf   = (u16*)wp; wp += (size_t)2048 * 2048 * 2;
  u16* xlnbf = (u16*)wp; wp += (size_t)2048 * 1024 * 2;

  const dim3 tb(256);
  const dim3 tb5(512);

  // ---- one mega prep launch: head + all layer weights + embed gather ----
  TBatch t{};
  int nj = 0, acc = 0;
  t.ids = ids;
  t.src[nj] = head; t.dst[nj] = headT;
  t.K[nj] = 1024; t.N[nj] = 32000; t.tx[nj] = 16;
  t.start[nj] = acc; acc += 16 * 500; ++nj;
  for (int i = 0; i < 2; ++i) {
    t.src[nj] = in_proj + (size_t)i * 1024 * 4096; t.dst[nj] = WiT[i];
    t.K[nj] = 1024; t.N[nj] = 4096; t.tx[nj] = 16;
    t.start[nj] = acc; acc += 16 * 64; ++nj;
    t.src[nj] = x_proj + (size_t)i * 2048 * 96; t.dst[nj] = WxT[i];
    t.K[nj] = 2048; t.N[nj] = 96; t.tx[nj] = 32;
    t.start[nj] = acc; acc += 32 * 2; ++nj;
    t.src[nj] = dt_w + (size_t)i * 64 * 2048; t.dst[nj] = WdtT[i];
    t.K[nj] = 64; t.N[nj] = 2048; t.tx[nj] = 1;
    t.start[nj] = acc; acc += 1 * 32; ++nj;
    t.src[nj] = out_proj + (size_t)i * 2048 * 1024; t.dst[nj] = WoT[i];
    t.K[nj] = 2048; t.N[nj] = 1024; t.tx[nj] = 32;
    t.start[nj] = acc; acc += 32 * 16; ++nj;
  }
  t.src[nj] = embed; t.dst[nj] = xbf;
  t.K[nj] = 0; t.N[nj] = 0; t.tx[nj] = -1;
  t.start[nj] = acc; acc += 2048; ++nj;
  t.start[nj] = acc;
  t.njobs = nj;
  transpose_batch<<<acc, tb, 0, stream>>>(t);

  for (int i = 0; i < 2; ++i) {
    gemm_bt<2><<<dim3(16, 32), tb, 0, stream>>>(xbf, WiT[i], nullptr, xzb, nullptr, 2048, 4096, 1024);
    conv_silu4<<<4096, tb, 0, stream>>>(xzb, conv_w + i * 2048 * 4, conv_b + i * 2048, ubf);
    xproj_split<<<dim3(16, 16), tb, 0, stream>>>(ubf, WxT[i], xpp);
    merge_x<<<768, tb, 0, stream>>>(xpp, dbc32, dtbf);
    gemm_bt<1><<<dim3(16, 16), tb, 0, stream>>>(dtbf, WdtT[i], nullptr, dbf, dt_b + i * 2048, 2048, 2048, 64);
    scan_pass1<<<512, tb, 0, stream>>>(dbf, ubf, dbc32, A_log + i * 2048 * 16, Pbh, Qbh);
    scan_prefix<<<256, tb, 0, stream>>>(Pbh, Qbh, Hph);
    scan_pass2<<<512, tb, 0, stream>>>(dbf, ubf, dbc32, xzb, A_log + i * 2048 * 16, Dp + i * 2048, Hph, ybf);
    outproj_split<<<dim3(16, 32), tb, 0, stream>>>(ybf, WoT[i], opp);
    if (i == 0) {
      merge_o1<<<2048, tb, 0, stream>>>(opp, xbf);
    } else {
      merge_o2_ln<<<2048, tb, 0, stream>>>(opp, ln_g, ln_bta, xlnbf);
    }
  }

  gemm256<<<dim3(8, 125), tb5, 0, stream>>>(xlnbf, headT, fout, 2048, 32000, 1024);
}

// Round 19
// 511.847 us; speedup vs baseline: 1.0409x; 1.0104x over previous
//
#include <hip/hip_runtime.h>

typedef unsigned short u16;
typedef __attribute__((ext_vector_type(8))) short bf16x8;
typedef __attribute__((ext_vector_type(4))) float f32x4;
typedef __attribute__((ext_vector_type(4))) u16 u16x4;
typedef __attribute__((ext_vector_type(8))) u16 u16x8;

#define DEV static __device__ __forceinline__

DEV u16 f2bf(float f) {
  union { float f; unsigned u; } v; v.f = f;
  unsigned r = (v.u + 0x7fffu + ((v.u >> 16) & 1u)) >> 16;
  return (u16)r;
}

DEV float bf2f(u16 v) { return __int_as_float(((int)v) << 16); }

DEV void gload_lds16(const void* g, void* l) {
  __builtin_amdgcn_global_load_lds(
      (const __attribute__((address_space(1))) unsigned int*)g,
      (__attribute__((address_space(3))) unsigned int*)l, 16, 0, 0);
}

// ---------------------------------------------------------------------------
// 256x256 8-wave MFMA GEMM — m201 8-phase (HEAD GEMM only). Plain C stores.
// ---------------------------------------------------------------------------
#define STGH(buf, mat, half, P, kt) { \
    const int r_ = (half) * 128 + sr0; \
    gload_lds16((P) + (size_t)r_ * K + (kt) + scs, &lds[buf][mat][r_][sc8]); \
    gload_lds16((P) + (size_t)(r_ + 64) * K + (kt) + scs, &lds[buf][mat][r_ + 64][sc8]); }
#define LDB(buf) _Pragma("unroll") for (int n = 0; n < 4; ++n) { \
    const int row = wn * 64 + n * 16 + lr; \
    _Pragma("unroll") for (int kk = 0; kk < 2; ++kk) \
      bfr[n][kk] = *(const bf16x8*)&lds[buf][1][row][(((kk << 2) | lq) ^ (row & 7)) << 3]; }
#define LDA(buf, p) _Pragma("unroll") for (int mi = 0; mi < 2; ++mi) { \
    const int row = wm * 128 + ((p) * 2 + mi) * 16 + lr; \
    _Pragma("unroll") for (int kk = 0; kk < 2; ++kk) \
      af[mi][kk] = *(const bf16x8*)&lds[buf][0][row][(((kk << 2) | lq) ^ (row & 7)) << 3]; }
#define MM(p) __builtin_amdgcn_s_setprio(1); \
  _Pragma("unroll") for (int kk = 0; kk < 2; ++kk) \
  _Pragma("unroll") for (int mi = 0; mi < 2; ++mi) \
  _Pragma("unroll") for (int n = 0; n < 4; ++n) \
    acc[(p) * 2 + mi][n] = __builtin_amdgcn_mfma_f32_16x16x32_bf16(af[mi][kk], bfr[n][kk], acc[(p) * 2 + mi][n], 0, 0, 0); \
  __builtin_amdgcn_s_setprio(0);
#define BAR() { __builtin_amdgcn_s_barrier(); asm volatile("" ::: "memory"); }
#define WLG() { asm volatile("s_waitcnt lgkmcnt(0)" ::: "memory"); __builtin_amdgcn_sched_barrier(0); }
#define VMC(n) asm volatile("s_waitcnt vmcnt(" #n ")" ::: "memory")

__global__ __launch_bounds__(512, 1)
void gemm256(const u16* __restrict__ A, const u16* __restrict__ BT,
             float* __restrict__ C, int M, int N, int K) {
  __shared__ u16 lds[2][2][256][64];   // [buf][A=0,B=1][row][k]
  const int t = threadIdx.x;
  const int l = t & 63;
  const int w = t >> 6;
  const int wm = w >> 2;        // 0..1
  const int wn = w & 3;         // 0..3
  const int lr = l & 15, lq = l >> 4;

  const int gn = N >> 8;
  const int nwg = gn << 3;
  const int orig = blockIdx.y * 8 + blockIdx.x;
  const int q = nwg >> 3;
  const int swz = (orig & 7) * q + (orig >> 3);
  const int bx = swz & 7;
  const int by = swz >> 3;

  const u16* Ap = A + (size_t)bx * 256 * K;
  const u16* Bp = BT + (size_t)by * 256 * K;
  const int sr0 = t >> 3;
  const int sc8 = (t & 7) << 3;
  const int scs = (((t & 7) ^ (sr0 & 7)) << 3);

  f32x4 acc[8][4];
#pragma unroll
  for (int m = 0; m < 8; ++m)
#pragma unroll
    for (int n = 0; n < 4; ++n) acc[m][n] = (f32x4){0.f, 0.f, 0.f, 0.f};

  const int NI = K >> 7;
  STGH(0, 1, 0, Bp, 0) STGH(0, 1, 1, Bp, 0)
  STGH(0, 0, 0, Ap, 0) STGH(0, 0, 1, Ap, 0)
  STGH(1, 1, 0, Bp, 64) STGH(1, 1, 1, Bp, 64)
  VMC(4);
  BAR();

  for (int ip = 0; ip < NI; ++ip) {
    const int k0 = ip << 7;
    const bool m2 = (k0 + 128) < K;
    const bool m3 = (k0 + 192) < K;
    bf16x8 bfr[4][2], af[2][2];
    LDB(0) LDA(0, 0)
    STGH(1, 0, 0, Ap, k0 + 64)
    BAR(); WLG(); MM(0) BAR();
    LDA(0, 1)
    STGH(1, 0, 1, Ap, k0 + 64)
    BAR(); WLG(); MM(1) BAR();
    LDA(0, 2)
    if (m2) STGH(0, 1, 0, Bp, k0 + 128)
    BAR(); WLG(); MM(2) BAR();
    LDA(0, 3)
    if (m2) STGH(0, 1, 1, Bp, k0 + 128)
    BAR(); WLG(); MM(3)
    if (m2) { VMC(4); } else { VMC(0); }
    BAR();
    LDB(1) LDA(1, 0)
    if (m2) STGH(0, 0, 0, Ap, k0 + 128)
    BAR(); WLG(); MM(0) BAR();
    LDA(1, 1)
    if (m2) STGH(0, 0, 1, Ap, k0 + 128)
    BAR(); WLG(); MM(1) BAR();
    LDA(1, 2)
    if (m3) STGH(1, 1, 0, Bp, k0 + 192)
    BAR(); WLG(); MM(2) BAR();
    LDA(1, 3)
    if (m3) STGH(1, 1, 1, Bp, k0 + 192)
    BAR(); WLG(); MM(3)
    if (m3) { VMC(4); } else { VMC(0); }
    BAR();
  }

  const int lg4 = lq * 4;
#pragma unroll
  for (int m = 0; m < 8; ++m) {
    const int grow0 = bx * 256 + wm * 128 + m * 16 + lg4;
#pragma unroll
    for (int n = 0; n < 4; ++n) {
      const int gcol = by * 256 + wn * 64 + n * 16 + lr;
#pragma unroll
      for (int r = 0; r < 4; ++r) {
        const size_t idx = (size_t)(grow0 + r) * N + gcol;
        C[idx] = acc[m][n][r];
      }
    }
  }
}
#undef STGH
#undef LDB
#undef LDA
#undef MM
#undef BAR
#undef WLG
#undef VMC

// ---------------------------------------------------------------------------
// 128x128 BK=64 GEMM.  EPI: 0 = f32 C; 1 = +bias, softplus, bf16 Cbf;
// 2 = plain bf16 Cbf.  gridDim.x MUST be 16; nwg % 8 == 0.
// ---------------------------------------------------------------------------
template<int EPI>
__global__ __launch_bounds__(256)
void gemm_bt(const u16* __restrict__ A, const u16* __restrict__ BT,
             float* __restrict__ C, u16* __restrict__ Cbf,
             const float* __restrict__ bias, int M, int N, int K) {
  __shared__ u16 As[128][64];
  __shared__ u16 Bs[128][64];
  const int t = threadIdx.x;
  const int l = t & 63;
  const int w = t >> 6;
  const int wr = (w >> 1) * 64;
  const int wc = (w & 1) * 64;

  const int nwg = gridDim.x * gridDim.y;
  const int orig = blockIdx.y * gridDim.x + blockIdx.x;
  const int swz = (orig & 7) * (nwg >> 3) + (orig >> 3);
  const int bx = swz & 15;
  const int by = swz >> 4;

  const size_t aoff = (size_t)bx * 128 * K;
  const size_t boff = (size_t)by * 128 * K;
  const int r0 = t >> 3;
  const int c0s = (((t & 7) ^ (r0 & 7)) << 3);
  const int c0l = (t & 7) << 3;
  const int lr = l & 15;
  const int lq = l >> 4;

  f32x4 acc[4][4];
#pragma unroll
  for (int i = 0; i < 4; ++i)
#pragma unroll
    for (int j = 0; j < 4; ++j) acc[i][j] = (f32x4){0.f, 0.f, 0.f, 0.f};

  for (int kt = 0; kt < K; kt += 64) {
    __syncthreads();
#pragma unroll
    for (int i = 0; i < 4; ++i) {
      const int r = r0 + i * 32;
      gload_lds16(A + aoff + (size_t)r * K + kt + c0s, &As[r][c0l]);
      gload_lds16(BT + boff + (size_t)r * K + kt + c0s, &Bs[r][c0l]);
    }
    __syncthreads();
#pragma unroll
    for (int kk = 0; kk < 2; ++kk) {
      bf16x8 af[4], bfr[4];
#pragma unroll
      for (int i = 0; i < 4; ++i) {
        const int row = wr + i * 16 + lr;
        af[i] = *(const bf16x8*)&As[row][(((kk << 2) | lq) ^ (row & 7)) << 3];
      }
#pragma unroll
      for (int j = 0; j < 4; ++j) {
        const int row = wc + j * 16 + lr;
        bfr[j] = *(const bf16x8*)&Bs[row][(((kk << 2) | lq) ^ (row & 7)) << 3];
      }
#pragma unroll
      for (int i = 0; i < 4; ++i)
#pragma unroll
        for (int j = 0; j < 4; ++j)
          acc[i][j] = __builtin_amdgcn_mfma_f32_16x16x32_bf16(af[i], bfr[j], acc[i][j], 0, 0, 0);
    }
  }

  const int lg4 = lq * 4;
#pragma unroll
  for (int i = 0; i < 4; ++i) {
    const int grow0 = bx * 128 + wr + i * 16 + lg4;
#pragma unroll
    for (int j = 0; j < 4; ++j) {
      const int gcol = by * 128 + wc + j * 16 + lr;
      float bv = 0.f;
      if (EPI == 1) bv = bias[gcol];
#pragma unroll
      for (int r = 0; r < 4; ++r) {
        float v = acc[i][j][r];
        if (EPI == 0) {
          C[(size_t)(grow0 + r) * N + gcol] = v;
        } else if (EPI == 1) {
          v += bv;
          v = fmaxf(v, 0.f) + log1pf(expf(-fabsf(v)));   // stable softplus
          Cbf[(size_t)(grow0 + r) * N + gcol] = f2bf(v);
        } else {
          Cbf[(size_t)(grow0 + r) * N + gcol] = f2bf(v);
        }
      }
    }
  }
}

// ---------------------------------------------------------------------------
// x_proj split-K 16: A=ubf[2048,2048], BT=WxT[128,2048] (both ld 2048).
// grid (16, 16): bx = row-tile, ch = K-chunk of 128. Partials to P[r][96]
// (padding cols 96-127 are zeros — not written).
// ---------------------------------------------------------------------------
__global__ __launch_bounds__(256)
void xproj_split(const u16* __restrict__ A, const u16* __restrict__ BT,
                 float* __restrict__ P) {
  __shared__ u16 As[128][64];
  __shared__ u16 Bs[128][64];
  const int t = threadIdx.x;
  const int l = t & 63;
  const int w = t >> 6;
  const int wr = (w >> 1) * 64;
  const int wc = (w & 1) * 64;
  const int bx = blockIdx.x;
  const int ch = blockIdx.y;
  const int kb = ch * 128;

  const size_t aoff = (size_t)bx * 128 * 2048 + kb;
  const int r0 = t >> 3;
  const int c0s = (((t & 7) ^ (r0 & 7)) << 3);
  const int c0l = (t & 7) << 3;
  const int lr = l & 15;
  const int lq = l >> 4;

  f32x4 acc[4][4];
#pragma unroll
  for (int i = 0; i < 4; ++i)
#pragma unroll
    for (int j = 0; j < 4; ++j) acc[i][j] = (f32x4){0.f, 0.f, 0.f, 0.f};

  for (int kt = 0; kt < 128; kt += 64) {
    __syncthreads();
#pragma unroll
    for (int i = 0; i < 4; ++i) {
      const int r = r0 + i * 32;
      gload_lds16(A + aoff + (size_t)r * 2048 + kt + c0s, &As[r][c0l]);
      gload_lds16(BT + (size_t)r * 2048 + kb + kt + c0s, &Bs[r][c0l]);
    }
    __syncthreads();
#pragma unroll
    for (int kk = 0; kk < 2; ++kk) {
      bf16x8 af[4], bfr[4];
#pragma unroll
      for (int i = 0; i < 4; ++i) {
        const int row = wr + i * 16 + lr;
        af[i] = *(const bf16x8*)&As[row][(((kk << 2) | lq) ^ (row & 7)) << 3];
      }
#pragma unroll
      for (int j = 0; j < 4; ++j) {
        const int row = wc + j * 16 + lr;
        bfr[j] = *(const bf16x8*)&Bs[row][(((kk << 2) | lq) ^ (row & 7)) << 3];
      }
#pragma unroll
      for (int i = 0; i < 4; ++i)
#pragma unroll
        for (int j = 0; j < 4; ++j)
          acc[i][j] = __builtin_amdgcn_mfma_f32_16x16x32_bf16(af[i], bfr[j], acc[i][j], 0, 0, 0);
    }
  }

  float* __restrict__ Pc = P + (size_t)ch * 196608;   // 2048*96
  const int lg4 = lq * 4;
#pragma unroll
  for (int i = 0; i < 4; ++i) {
    const int grow0 = bx * 128 + wr + i * 16 + lg4;
#pragma unroll
    for (int j = 0; j < 4; ++j) {
      const int gcol = wc + j * 16 + lr;
      if (gcol < 96) {
#pragma unroll
        for (int r = 0; r < 4; ++r)
          Pc[(size_t)(grow0 + r) * 96 + gcol] = acc[i][j][r];
      }
    }
  }
}

// merge 16 x_proj partials -> dtbf bf16 [r][64] + compact dbc32 f32 [r][32]
__global__ __launch_bounds__(256)
void merge_x(const float* __restrict__ P, float* __restrict__ dbc32,
             u16* __restrict__ dtbf) {
  const int idx = blockIdx.x * 256 + threadIdx.x;   // 196608
  float s = 0.f;
#pragma unroll
  for (int ch = 0; ch < 16; ++ch) s += P[(size_t)ch * 196608 + idx];
  const int r = idx / 96, c = idx - r * 96;
  if (c < 64) dtbf[r * 64 + c] = f2bf(s);
  else        dbc32[r * 32 + (c - 64)] = s;
}

// ---------------------------------------------------------------------------
// out_proj split-K 4: A=ybf[2048,2048], BT=WoT[1024,2048] (ld 2048).
// grid (16, 32): bx = row-tile, y&7 = N-tile, y>>3 = K-quarter of 512.
// Partials stored BF16 (halves the carrier round-trip; r18-validated mech).
// ---------------------------------------------------------------------------
__global__ __launch_bounds__(256)
void outproj_split(const u16* __restrict__ A, const u16* __restrict__ BT,
                   u16* __restrict__ P) {
  __shared__ u16 As[128][64];
  __shared__ u16 Bs[128][64];
  const int t = threadIdx.x;
  const int l = t & 63;
  const int w = t >> 6;
  const int wr = (w >> 1) * 64;
  const int wc = (w & 1) * 64;
  const int bx = blockIdx.x;
  const int byn = blockIdx.y & 7;
  const int ch = blockIdx.y >> 3;      // 0..3
  const int kb = ch * 512;

  const size_t aoff = (size_t)bx * 128 * 2048 + kb;
  const size_t boff = (size_t)byn * 128 * 2048 + kb;
  const int r0 = t >> 3;
  const int c0s = (((t & 7) ^ (r0 & 7)) << 3);
  const int c0l = (t & 7) << 3;
  const int lr = l & 15;
  const int lq = l >> 4;

  f32x4 acc[4][4];
#pragma unroll
  for (int i = 0; i < 4; ++i)
#pragma unroll
    for (int j = 0; j < 4; ++j) acc[i][j] = (f32x4){0.f, 0.f, 0.f, 0.f};

  for (int kt = 0; kt < 512; kt += 64) {
    __syncthreads();
#pragma unroll
    for (int i = 0; i < 4; ++i) {
      const int r = r0 + i * 32;
      gload_lds16(A + aoff + (size_t)r * 2048 + kt + c0s, &As[r][c0l]);
      gload_lds16(BT + boff + (size_t)r * 2048 + kt + c0s, &Bs[r][c0l]);
    }
    __syncthreads();
#pragma unroll
    for (int kk = 0; kk < 2; ++kk) {
      bf16x8 af[4], bfr[4];
#pragma unroll
      for (int i = 0; i < 4; ++i) {
        const int row = wr + i * 16 + lr;
        af[i] = *(const bf16x8*)&As[row][(((kk << 2) | lq) ^ (row & 7)) << 3];
      }
#pragma unroll
      for (int j = 0; j < 4; ++j) {
        const int row = wc + j * 16 + lr;
        bfr[j] = *(const bf16x8*)&Bs[row][(((kk << 2) | lq) ^ (row & 7)) << 3];
      }
#pragma unroll
      for (int i = 0; i < 4; ++i)
#pragma unroll
        for (int j = 0; j < 4; ++j)
          acc[i][j] = __builtin_amdgcn_mfma_f32_16x16x32_bf16(af[i], bfr[j], acc[i][j], 0, 0, 0);
    }
  }

  u16* __restrict__ Pc = P + (size_t)ch * 2097152;
  const int lg4 = lq * 4;
#pragma unroll
  for (int i = 0; i < 4; ++i) {
    const int grow0 = bx * 128 + wr + i * 16 + lg4;
#pragma unroll
    for (int j = 0; j < 4; ++j) {
      const int gcol = byn * 128 + wc + j * 16 + lr;
#pragma unroll
      for (int r = 0; r < 4; ++r)
        Pc[(size_t)(grow0 + r) * 1024 + gcol] = f2bf(acc[i][j][r]);
    }
  }
}

// layer-1 merge: xbf = bf16(p0+p1+p2+p3), partials bf16
__global__ __launch_bounds__(256)
void merge_o1(const u16* __restrict__ P, u16* __restrict__ xbf) {
  const int i4 = (blockIdx.x * 256 + threadIdx.x) * 4;   // 2048 blocks
  float v0 = 0.f, v1 = 0.f, v2 = 0.f, v3 = 0.f;
#pragma unroll
  for (int ch = 0; ch < 4; ++ch) {
    const u16x4 b = *(const u16x4*)(P + (size_t)ch * 2097152 + i4);
    v0 += bf2f(b[0]); v1 += bf2f(b[1]); v2 += bf2f(b[2]); v3 += bf2f(b[3]);
  }
  u16x4 o = { f2bf(v0), f2bf(v1), f2bf(v2), f2bf(v3) };
  *(u16x4*)(xbf + i4) = o;
}

// layer-2 merge + final LayerNorm fused: xlnbf = bf16(LN(sum of 4 bf16 partials))
__global__ __launch_bounds__(256)
void merge_o2_ln(const u16* __restrict__ P, const float* __restrict__ g,
                 const float* __restrict__ bta, u16* __restrict__ out) {
  __shared__ float red1[4], red2[4];
  const int r = blockIdx.x;
  const int tid = threadIdx.x;
  const int lane = tid & 63, wid = tid >> 6;
  const int c4 = tid * 4;
  float v0 = 0.f, v1 = 0.f, v2 = 0.f, v3 = 0.f;
#pragma unroll
  for (int ch = 0; ch < 4; ++ch) {
    const u16x4 b = *(const u16x4*)(P + (size_t)ch * 2097152 + (size_t)r * 1024 + c4);
    v0 += bf2f(b[0]); v1 += bf2f(b[1]); v2 += bf2f(b[2]); v3 += bf2f(b[3]);
  }
  float s = v0 + v1 + v2 + v3;
#pragma unroll
  for (int m = 1; m < 64; m <<= 1) s += __shfl_xor(s, m, 64);
  if (lane == 0) red1[wid] = s;
  __syncthreads();
  const float mu = (red1[0] + red1[1] + red1[2] + red1[3]) * (1.f / 1024.f);
  const float d0 = v0 - mu, d1 = v1 - mu, d2 = v2 - mu, d3 = v3 - mu;
  float qv = d0 * d0 + d1 * d1 + d2 * d2 + d3 * d3;
#pragma unroll
  for (int m = 1; m < 64; m <<= 1) qv += __shfl_xor(qv, m, 64);
  if (lane == 0) red2[wid] = qv;
  __syncthreads();
  const float rs = rsqrtf((red2[0] + red2[1] + red2[2] + red2[3]) * (1.f / 1024.f) + 1e-5f);
  const float4 gv = *(const float4*)(g + c4);
  const float4 bv = *(const float4*)(bta + c4);
  u16x4 o = { f2bf(d0 * rs * gv.x + bv.x), f2bf(d1 * rs * gv.y + bv.y),
              f2bf(d2 * rs * gv.z + bv.z), f2bf(d3 * rs * gv.w + bv.w) };
  *(u16x4*)(out + (size_t)r * 1024 + c4) = o;
}

// ---------------------------------------------------------------------------
// mega prep batch: 64x64 tiles; 256B-contiguous NT reads, u16x8 stores.
// tx<0: embed gather (lt = row).
// ---------------------------------------------------------------------------
struct TBatch {
  const float* src[10];
  u16* dst[10];
  int K[10], N[10], tx[10];
  int start[11];
  int njobs;
  const int* ids;
};

__global__ __launch_bounds__(256)
void transpose_batch(TBatch tb) {
  const int tile = blockIdx.x;
  int j = 0;
  while (j + 1 < tb.njobs && tile >= tb.start[j + 1]) ++j;
  const int lt = tile - tb.start[j];

  if (tb.tx[j] < 0) {   // embed gather: row lt, 1024 cols via float4
    const int c = threadIdx.x * 4;
    const int id = tb.ids[lt];
    const float4 v = *(const float4*)(tb.src[j] + (size_t)id * 1024 + c);
    u16x4 o = { f2bf(v.x), f2bf(v.y), f2bf(v.z), f2bf(v.w) };
    *(u16x4*)(tb.dst[j] + (size_t)lt * 1024 + c) = o;
    return;
  }

  const int K = tb.K[j];
  const int N = tb.N[j];
  const int kb = (lt % tb.tx[j]) * 64;
  const int nb = (lt / tb.tx[j]) * 64;
  const float* __restrict__ in = tb.src[j];
  u16* __restrict__ out = tb.dst[j];

  __shared__ float ts[64][65];
  const int rr = threadIdx.x >> 4;        // 0..15
  const int cc = (threadIdx.x & 15) * 4;  // 0..60
  const int gn = nb + cc;
#pragma unroll
  for (int s = 0; s < 4; ++s) {
    const int k = kb + s * 16 + rr;
    f32x4 v = { 0.f, 0.f, 0.f, 0.f };
    if (gn < N) v = __builtin_nontemporal_load((const f32x4*)(in + (size_t)k * N + gn));
    ts[s * 16 + rr][cc + 0] = v[0];
    ts[s * 16 + rr][cc + 1] = v[1];
    ts[s * 16 + rr][cc + 2] = v[2];
    ts[s * 16 + rr][cc + 3] = v[3];
  }
  __syncthreads();
  const int k8 = (threadIdx.x & 7) * 8;
#pragma unroll
  for (int s = 0; s < 2; ++s) {
    const int nl = (threadIdx.x >> 3) + s * 32;   // 0..63
    u16x8 o;
#pragma unroll
    for (int i = 0; i < 8; ++i) o[i] = f2bf(ts[k8 + i][nl]);
    *(u16x8*)(out + (size_t)(nb + nl) * K + kb + k8) = o;
  }
}

// u = silu(causal_conv(xin) + cb) -> bf16.  xz is bf16. 4 ch/thread.
__global__ __launch_bounds__(256)
void conv_silu4(const u16* __restrict__ xzb, const float* __restrict__ cw,
                const float* __restrict__ cb, u16* __restrict__ ubf) {
  const int i4 = (blockIdx.x * 256 + threadIdx.x) * 4;   // grid 4096
  const int d = i4 & 2047;
  const int r = i4 >> 11;
  const int t = r & 1023;
  float4 acc = *(const float4*)(cb + d);
  const float4 w0 = *(const float4*)(cw + (d + 0) * 4);
  const float4 w1 = *(const float4*)(cw + (d + 1) * 4);
  const float4 w2 = *(const float4*)(cw + (d + 2) * 4);
  const float4 w3 = *(const float4*)(cw + (d + 3) * 4);
#pragma unroll
  for (int k = 0; k < 4; ++k) {
    const int tt = t - 3 + k;
    if (tt >= 0) {
      const u16x4 x4 = *(const u16x4*)(xzb + (size_t)(r - 3 + k) * 4096 + d);
      acc.x = fmaf(bf2f(x4[0]), ((const float*)&w0)[k], acc.x);
      acc.y = fmaf(bf2f(x4[1]), ((const float*)&w1)[k], acc.y);
      acc.z = fmaf(bf2f(x4[2]), ((const float*)&w2)[k], acc.z);
      acc.w = fmaf(bf2f(x4[3]), ((const float*)&w3)[k], acc.w);
    }
  }
  u16x4 o = { f2bf(acc.x / (1.f + __expf(-acc.x))), f2bf(acc.y / (1.f + __expf(-acc.y))),
              f2bf(acc.z / (1.f + __expf(-acc.z))), f2bf(acc.w / (1.f + __expf(-acc.w))) };
  *(u16x4*)(ubf + i4) = o;
}

// ---------------------------------------------------------------------------
// selective scan, n-in-registers; delta/u/z read as bf16 (coalesced 2B/lane).
// 32 chunks x 32 steps; grid = 2b x 8dt x 32ch = 512 blocks (2 blocks/CU).
// dbc32 compact layout [r][32]: B = cols 0-15, C = cols 16-31.
// Chunk-state buffers Pb/Qb/Hp stored as bf16.
// ---------------------------------------------------------------------------
__global__ __launch_bounds__(256)
void scan_pass1(const u16* __restrict__ deltab, const u16* __restrict__ ub,
                const float* __restrict__ dbc32, const float* __restrict__ A_log,
                u16* __restrict__ Pb, u16* __restrict__ Qb) {
  const int blk = blockIdx.x;
  const int ch = blk & 31;
  if (ch == 31) return;          // last chunk's (P,Q) never consumed
  const int dt = (blk >> 5) & 7;
  const int b = blk >> 8;
  const int d = dt * 256 + threadIdx.x;

  float Ac[16], h[16], P[16];
#pragma unroll
  for (int n = 0; n < 16; ++n) {
    Ac[n] = -expf(A_log[d * 16 + n]) * 1.44269504f;
    h[n] = 0.f;
    P[n] = 1.f;
  }
  const int r0 = b * 1024 + ch * 32;
  for (int j = 0; j < 32; ++j) {
    const size_t r = r0 + j;
    const float dlt = bf2f(deltab[r * 2048 + d]);
    const float uu = bf2f(ub[r * 2048 + d]);
    const float du = dlt * uu;
    const float4 B0 = *(const float4*)(dbc32 + r * 32 + 0);
    const float4 B1 = *(const float4*)(dbc32 + r * 32 + 4);
    const float4 B2 = *(const float4*)(dbc32 + r * 32 + 8);
    const float4 B3 = *(const float4*)(dbc32 + r * 32 + 12);
    const float Bv[16] = { B0.x, B0.y, B0.z, B0.w, B1.x, B1.y, B1.z, B1.w,
                           B2.x, B2.y, B2.z, B2.w, B3.x, B3.y, B3.z, B3.w };
#pragma unroll
    for (int n = 0; n < 16; ++n) {
      const float da = exp2f(dlt * Ac[n]);
      P[n] *= da;
      h[n] = fmaf(da, h[n], du * Bv[n]);
    }
  }
  const size_t o = ((size_t)ch * 4096 + b * 2048 + d) * 16;
  u16x8 p0, p1, q0, q1;
#pragma unroll
  for (int n = 0; n < 8; ++n) { p0[n] = f2bf(P[n]); p1[n] = f2bf(P[n + 8]);
                                q0[n] = f2bf(h[n]); q1[n] = f2bf(h[n + 8]); }
  *(u16x8*)(Pb + o) = p0; *(u16x8*)(Pb + o + 8) = p1;
  *(u16x8*)(Qb + o) = q0; *(u16x8*)(Qb + o + 8) = q1;
}

// fold chunk (P,Q) into per-chunk entry states: Hp[ch] = state entering ch.
__global__ __launch_bounds__(256)
void scan_prefix(const u16* __restrict__ Pb, const u16* __restrict__ Qb,
                 u16* __restrict__ Hp) {
  const int tid = blockIdx.x * 256 + threadIdx.x;   // 65536
  float h = 0.f;
  Hp[tid] = 0;
  for (int ch = 0; ch < 31; ++ch) {
    const size_t o = (size_t)ch * 65536 + tid;
    h = fmaf(bf2f(Pb[o]), h, bf2f(Qb[o]));
    Hp[o + 65536] = f2bf(h);
  }
}

__global__ __launch_bounds__(256)
void scan_pass2(const u16* __restrict__ deltab, const u16* __restrict__ ub,
                const float* __restrict__ dbc32, const u16* __restrict__ xzb,
                const float* __restrict__ A_log, const float* __restrict__ Dp,
                const u16* __restrict__ Hp, u16* __restrict__ ybf) {
  const int blk = blockIdx.x;
  const int ch = blk & 31;
  const int dt = (blk >> 5) & 7;
  const int b = blk >> 8;
  const int d = dt * 256 + threadIdx.x;

  float Ac[16], h[16];
  const size_t ho = ((size_t)ch * 4096 + b * 2048 + d) * 16;
#pragma unroll
  for (int n = 0; n < 16; ++n) {
    Ac[n] = -expf(A_log[d * 16 + n]) * 1.44269504f;
    h[n] = bf2f(Hp[ho + n]);
  }
  const float Dd = Dp[d];

  const int r0 = b * 1024 + ch * 32;
  for (int j = 0; j < 32; ++j) {
    const size_t r = r0 + j;
    const float dlt = bf2f(deltab[r * 2048 + d]);
    const float uu = bf2f(ub[r * 2048 + d]);
    const float zz = bf2f(xzb[r * 4096 + 2048 + d]);
    const float du = dlt * uu;
    const float4 B0 = *(const float4*)(dbc32 + r * 32 + 0);
    const float4 B1 = *(const float4*)(dbc32 + r * 32 + 4);
    const float4 B2 = *(const float4*)(dbc32 + r * 32 + 8);
    const float4 B3 = *(const float4*)(dbc32 + r * 32 + 12);
    const float4 C0 = *(const float4*)(dbc32 + r * 32 + 16);
    const float4 C1 = *(const float4*)(dbc32 + r * 32 + 20);
    const float4 C2 = *(const float4*)(dbc32 + r * 32 + 24);
    const float4 C3 = *(const float4*)(dbc32 + r * 32 + 28);
    const float Bv[16] = { B0.x, B0.y, B0.z, B0.w, B1.x, B1.y, B1.z, B1.w,
                           B2.x, B2.y, B2.z, B2.w, B3.x, B3.y, B3.z, B3.w };
    const float Cv[16] = { C0.x, C0.y, C0.z, C0.w, C1.x, C1.y, C1.z, C1.w,
                           C2.x, C2.y, C2.z, C2.w, C3.x, C3.y, C3.z, C3.w };
    float p0 = 0.f, p1 = 0.f, p2 = 0.f, p3 = 0.f;
#pragma unroll
    for (int n = 0; n < 16; n += 4) {
      float da;
      da = exp2f(dlt * Ac[n + 0]); h[n + 0] = fmaf(da, h[n + 0], du * Bv[n + 0]); p0 = fmaf(h[n + 0], Cv[n + 0], p0);
      da = exp2f(dlt * Ac[n + 1]); h[n + 1] = fmaf(da, h[n + 1], du * Bv[n + 1]); p1 = fmaf(h[n + 1], Cv[n + 1], p1);
      da = exp2f(dlt * Ac[n + 2]); h[n + 2] = fmaf(da, h[n + 2], du * Bv[n + 2]); p2 = fmaf(h[n + 2], Cv[n + 2], p2);
      da = exp2f(dlt * Ac[n + 3]); h[n + 3] = fmaf(da, h[n + 3], du * Bv[n + 3]); p3 = fmaf(h[n + 3], Cv[n + 3], p3);
    }
    const float p = (p0 + p1) + (p2 + p3);
    const float yv = (p + uu * Dd) * (zz / (1.f + __expf(-zz)));
    ybf[r * 2048 + d] = f2bf(yv);
  }
}

// ---------------------------------------------------------------------------
extern "C" void kernel_launch(void* const* d_in, const int* in_sizes, int n_in,
                              void* d_out, int out_size, void* d_ws, size_t ws_size,
                              hipStream_t stream) {
  (void)in_sizes; (void)n_in; (void)out_size; (void)ws_size;
  const int*   ids      = (const int*)d_in[0];
  const float* embed    = (const float*)d_in[1];
  const float* in_proj  = (const float*)d_in[2];
  const float* conv_w   = (const float*)d_in[3];
  const float* conv_b   = (const float*)d_in[4];
  const float* x_proj   = (const float*)d_in[5];
  const float* dt_w     = (const float*)d_in[6];
  const float* dt_b     = (const float*)d_in[7];
  const float* A_log    = (const float*)d_in[8];
  const float* Dp       = (const float*)d_in[9];
  const float* out_proj = (const float*)d_in[10];
  const float* ln_g     = (const float*)d_in[11];
  const float* ln_bta   = (const float*)d_in[12];
  const float* head     = (const float*)d_in[13];

  // f32 scratch inside d_out (all consumed before head GEMM overwrites)
  float* fout  = (float*)d_out;
  float* dbc32 = fout + 16777216;   // 65,536
  float* xpp   = fout + 17039360;   // 16 * 196,608 = 3,145,728 (ends 20,185,088)

  // bf16 scratch in the dead tail of d_out (dead before head GEMM writes)
  u16* tail = (u16*)(fout + 21000000);
  u16* WiT[2]  = { tail,                tail + 4194304 };
  u16* WxT[2]  = { tail + 8388608,      tail + 8650752 };
  u16* WdtT[2] = { tail + 8912896,      tail + 9043968 };
  u16* WoT[2]  = { tail + 9175040,      tail + 11272192 };
  u16* dbf     = tail + 13369344;      // 4,194,304 u16 (bf16 delta)
  u16* xzb     = tail + 17563648;      // 8,388,608 u16
  u16* Pbh     = tail + 25952256;      // 2,097,152 u16 (bf16 chunk P)
  u16* Qbh     = tail + 28049408;      // 2,097,152 u16 (bf16 chunk Q)
  u16* Hph     = tail + 30146560;      // 2,097,152 u16 (bf16 entry state)
  u16* oppb    = tail + 32243712;      // 4 * 2,097,152 u16 = 8,388,608 (bf16 opp)
                                       // ends 40,632,320 u16 = 20,316,160 f32
                                       // (tail base 21M f32 + 20.3M f32 < 65.5M f32)

  // bf16 scratch in d_ws
  char* wp = (char*)d_ws;
  u16* headT = (u16*)wp; wp += (size_t)32000 * 1024 * 2;
  u16* xbf   = (u16*)wp; wp += (size_t)2048 * 1024 * 2;
  u16* ubf   = (u16*)wp; wp += (size_t)2048 * 2048 * 2;
  u16* dtbf  = (u16*)wp; wp += (size_t)2048 * 64 * 2;
  u16* ybf   = (u16*)wp; wp += (size_t)2048 * 2048 * 2;
  u16* xlnbf = (u16*)wp; wp += (size_t)2048 * 1024 * 2;

  const dim3 tb(256);
  const dim3 tb5(512);

  // ---- one mega prep launch: head + all layer weights + embed gather ----
  TBatch t{};
  int nj = 0, acc = 0;
  t.ids = ids;
  t.src[nj] = head; t.dst[nj] = headT;
  t.K[nj] = 1024; t.N[nj] = 32000; t.tx[nj] = 16;
  t.start[nj] = acc; acc += 16 * 500; ++nj;
  for (int i = 0; i < 2; ++i) {
    t.src[nj] = in_proj + (size_t)i * 1024 * 4096; t.dst[nj] = WiT[i];
    t.K[nj] = 1024; t.N[nj] = 4096; t.tx[nj] = 16;
    t.start[nj] = acc; acc += 16 * 64; ++nj;
    t.src[nj] = x_proj + (size_t)i * 2048 * 96; t.dst[nj] = WxT[i];
    t.K[nj] = 2048; t.N[nj] = 96; t.tx[nj] = 32;
    t.start[nj] = acc; acc += 32 * 2; ++nj;
    t.src[nj] = dt_w + (size_t)i * 64 * 2048; t.dst[nj] = WdtT[i];
    t.K[nj] = 64; t.N[nj] = 2048; t.tx[nj] = 1;
    t.start[nj] = acc; acc += 1 * 32; ++nj;
    t.src[nj] = out_proj + (size_t)i * 2048 * 1024; t.dst[nj] = WoT[i];
    t.K[nj] = 2048; t.N[nj] = 1024; t.tx[nj] = 32;
    t.start[nj] = acc; acc += 32 * 16; ++nj;
  }
  t.src[nj] = embed; t.dst[nj] = xbf;
  t.K[nj] = 0; t.N[nj] = 0; t.tx[nj] = -1;
  t.start[nj] = acc; acc += 2048; ++nj;
  t.start[nj] = acc;
  t.njobs = nj;
  transpose_batch<<<acc, tb, 0, stream>>>(t);

  for (int i = 0; i < 2; ++i) {
    gemm_bt<2><<<dim3(16, 32), tb, 0, stream>>>(xbf, WiT[i], nullptr, xzb, nullptr, 2048, 4096, 1024);
    conv_silu4<<<4096, tb, 0, stream>>>(xzb, conv_w + i * 2048 * 4, conv_b + i * 2048, ubf);
    xproj_split<<<dim3(16, 16), tb, 0, stream>>>(ubf, WxT[i], xpp);
    merge_x<<<768, tb, 0, stream>>>(xpp, dbc32, dtbf);
    gemm_bt<1><<<dim3(16, 16), tb, 0, stream>>>(dtbf, WdtT[i], nullptr, dbf, dt_b + i * 2048, 2048, 2048, 64);
    scan_pass1<<<512, tb, 0, stream>>>(dbf, ubf, dbc32, A_log + i * 2048 * 16, Pbh, Qbh);
    scan_prefix<<<256, tb, 0, stream>>>(Pbh, Qbh, Hph);
    scan_pass2<<<512, tb, 0, stream>>>(dbf, ubf, dbc32, xzb, A_log + i * 2048 * 16, Dp + i * 2048, Hph, ybf);
    outproj_split<<<dim3(16, 32), tb, 0, stream>>>(ybf, WoT[i], oppb);
    if (i == 0) {
      merge_o1<<<2048, tb, 0, stream>>>(oppb, xbf);
    } else {
      merge_o2_ln<<<2048, tb, 0, stream>>>(oppb, ln_g, ln_bta, xlnbf);
    }
  }

  gemm256<<<dim3(8, 125), tb5, 0, stream>>>(xlnbf, headT, fout, 2048, 32000, 1024);
}

// Round 20
// 510.390 us; speedup vs baseline: 1.0439x; 1.0029x over previous
//
#include <hip/hip_runtime.h>

typedef unsigned short u16;
typedef __attribute__((ext_vector_type(8))) short bf16x8;
typedef __attribute__((ext_vector_type(4))) float f32x4;
typedef __attribute__((ext_vector_type(4))) u16 u16x4;
typedef __attribute__((ext_vector_type(8))) u16 u16x8;

#define DEV static __device__ __forceinline__

DEV u16 f2bf(float f) {
  union { float f; unsigned u; } v; v.f = f;
  unsigned r = (v.u + 0x7fffu + ((v.u >> 16) & 1u)) >> 16;
  return (u16)r;
}

DEV float bf2f(u16 v) { return __int_as_float(((int)v) << 16); }

DEV void gload_lds16(const void* g, void* l) {
  __builtin_amdgcn_global_load_lds(
      (const __attribute__((address_space(1))) unsigned int*)g,
      (__attribute__((address_space(3))) unsigned int*)l, 16, 0, 0);
}

// ---------------------------------------------------------------------------
// 256x256 8-wave MFMA GEMM — m201 8-phase (HEAD GEMM only). Plain C stores.
// ---------------------------------------------------------------------------
#define STGH(buf, mat, half, P, kt) { \
    const int r_ = (half) * 128 + sr0; \
    gload_lds16((P) + (size_t)r_ * K + (kt) + scs, &lds[buf][mat][r_][sc8]); \
    gload_lds16((P) + (size_t)(r_ + 64) * K + (kt) + scs, &lds[buf][mat][r_ + 64][sc8]); }
#define LDB(buf) _Pragma("unroll") for (int n = 0; n < 4; ++n) { \
    const int row = wn * 64 + n * 16 + lr; \
    _Pragma("unroll") for (int kk = 0; kk < 2; ++kk) \
      bfr[n][kk] = *(const bf16x8*)&lds[buf][1][row][(((kk << 2) | lq) ^ (row & 7)) << 3]; }
#define LDA(buf, p) _Pragma("unroll") for (int mi = 0; mi < 2; ++mi) { \
    const int row = wm * 128 + ((p) * 2 + mi) * 16 + lr; \
    _Pragma("unroll") for (int kk = 0; kk < 2; ++kk) \
      af[mi][kk] = *(const bf16x8*)&lds[buf][0][row][(((kk << 2) | lq) ^ (row & 7)) << 3]; }
#define MM(p) __builtin_amdgcn_s_setprio(1); \
  _Pragma("unroll") for (int kk = 0; kk < 2; ++kk) \
  _Pragma("unroll") for (int mi = 0; mi < 2; ++mi) \
  _Pragma("unroll") for (int n = 0; n < 4; ++n) \
    acc[(p) * 2 + mi][n] = __builtin_amdgcn_mfma_f32_16x16x32_bf16(af[mi][kk], bfr[n][kk], acc[(p) * 2 + mi][n], 0, 0, 0); \
  __builtin_amdgcn_s_setprio(0);
#define BAR() { __builtin_amdgcn_s_barrier(); asm volatile("" ::: "memory"); }
#define WLG() { asm volatile("s_waitcnt lgkmcnt(0)" ::: "memory"); __builtin_amdgcn_sched_barrier(0); }
#define VMC(n) asm volatile("s_waitcnt vmcnt(" #n ")" ::: "memory")

__global__ __launch_bounds__(512, 1)
void gemm256(const u16* __restrict__ A, const u16* __restrict__ BT,
             float* __restrict__ C, int M, int N, int K) {
  __shared__ u16 lds[2][2][256][64];   // [buf][A=0,B=1][row][k]
  const int t = threadIdx.x;
  const int l = t & 63;
  const int w = t >> 6;
  const int wm = w >> 2;        // 0..1
  const int wn = w & 3;         // 0..3
  const int lr = l & 15, lq = l >> 4;

  const int gn = N >> 8;
  const int nwg = gn << 3;
  const int orig = blockIdx.y * 8 + blockIdx.x;
  const int q = nwg >> 3;
  const int swz = (orig & 7) * q + (orig >> 3);
  const int bx = swz & 7;
  const int by = swz >> 3;

  const u16* Ap = A + (size_t)bx * 256 * K;
  const u16* Bp = BT + (size_t)by * 256 * K;
  const int sr0 = t >> 3;
  const int sc8 = (t & 7) << 3;
  const int scs = (((t & 7) ^ (sr0 & 7)) << 3);

  f32x4 acc[8][4];
#pragma unroll
  for (int m = 0; m < 8; ++m)
#pragma unroll
    for (int n = 0; n < 4; ++n) acc[m][n] = (f32x4){0.f, 0.f, 0.f, 0.f};

  const int NI = K >> 7;
  STGH(0, 1, 0, Bp, 0) STGH(0, 1, 1, Bp, 0)
  STGH(0, 0, 0, Ap, 0) STGH(0, 0, 1, Ap, 0)
  STGH(1, 1, 0, Bp, 64) STGH(1, 1, 1, Bp, 64)
  VMC(4);
  BAR();

  for (int ip = 0; ip < NI; ++ip) {
    const int k0 = ip << 7;
    const bool m2 = (k0 + 128) < K;
    const bool m3 = (k0 + 192) < K;
    bf16x8 bfr[4][2], af[2][2];
    LDB(0) LDA(0, 0)
    STGH(1, 0, 0, Ap, k0 + 64)
    BAR(); WLG(); MM(0) BAR();
    LDA(0, 1)
    STGH(1, 0, 1, Ap, k0 + 64)
    BAR(); WLG(); MM(1) BAR();
    LDA(0, 2)
    if (m2) STGH(0, 1, 0, Bp, k0 + 128)
    BAR(); WLG(); MM(2) BAR();
    LDA(0, 3)
    if (m2) STGH(0, 1, 1, Bp, k0 + 128)
    BAR(); WLG(); MM(3)
    if (m2) { VMC(4); } else { VMC(0); }
    BAR();
    LDB(1) LDA(1, 0)
    if (m2) STGH(0, 0, 0, Ap, k0 + 128)
    BAR(); WLG(); MM(0) BAR();
    LDA(1, 1)
    if (m2) STGH(0, 0, 1, Ap, k0 + 128)
    BAR(); WLG(); MM(1) BAR();
    LDA(1, 2)
    if (m3) STGH(1, 1, 0, Bp, k0 + 192)
    BAR(); WLG(); MM(2) BAR();
    LDA(1, 3)
    if (m3) STGH(1, 1, 1, Bp, k0 + 192)
    BAR(); WLG(); MM(3)
    if (m3) { VMC(4); } else { VMC(0); }
    BAR();
  }

  const int lg4 = lq * 4;
#pragma unroll
  for (int m = 0; m < 8; ++m) {
    const int grow0 = bx * 256 + wm * 128 + m * 16 + lg4;
#pragma unroll
    for (int n = 0; n < 4; ++n) {
      const int gcol = by * 256 + wn * 64 + n * 16 + lr;
#pragma unroll
      for (int r = 0; r < 4; ++r) {
        const size_t idx = (size_t)(grow0 + r) * N + gcol;
        C[idx] = acc[m][n][r];
      }
    }
  }
}
#undef STGH
#undef LDB
#undef LDA
#undef MM
#undef BAR
#undef WLG
#undef VMC

// ---------------------------------------------------------------------------
// 128x128 BK=64 GEMM.  EPI: 0 = f32 C; 1 = +bias, softplus, bf16 Cbf;
// 2 = plain bf16 Cbf.  gridDim.x MUST be 16; nwg % 8 == 0.
// ---------------------------------------------------------------------------
template<int EPI>
__global__ __launch_bounds__(256)
void gemm_bt(const u16* __restrict__ A, const u16* __restrict__ BT,
             float* __restrict__ C, u16* __restrict__ Cbf,
             const float* __restrict__ bias, int M, int N, int K) {
  __shared__ u16 As[128][64];
  __shared__ u16 Bs[128][64];
  const int t = threadIdx.x;
  const int l = t & 63;
  const int w = t >> 6;
  const int wr = (w >> 1) * 64;
  const int wc = (w & 1) * 64;

  const int nwg = gridDim.x * gridDim.y;
  const int orig = blockIdx.y * gridDim.x + blockIdx.x;
  const int swz = (orig & 7) * (nwg >> 3) + (orig >> 3);
  const int bx = swz & 15;
  const int by = swz >> 4;

  const size_t aoff = (size_t)bx * 128 * K;
  const size_t boff = (size_t)by * 128 * K;
  const int r0 = t >> 3;
  const int c0s = (((t & 7) ^ (r0 & 7)) << 3);
  const int c0l = (t & 7) << 3;
  const int lr = l & 15;
  const int lq = l >> 4;

  f32x4 acc[4][4];
#pragma unroll
  for (int i = 0; i < 4; ++i)
#pragma unroll
    for (int j = 0; j < 4; ++j) acc[i][j] = (f32x4){0.f, 0.f, 0.f, 0.f};

  for (int kt = 0; kt < K; kt += 64) {
    __syncthreads();
#pragma unroll
    for (int i = 0; i < 4; ++i) {
      const int r = r0 + i * 32;
      gload_lds16(A + aoff + (size_t)r * K + kt + c0s, &As[r][c0l]);
      gload_lds16(BT + boff + (size_t)r * K + kt + c0s, &Bs[r][c0l]);
    }
    __syncthreads();
#pragma unroll
    for (int kk = 0; kk < 2; ++kk) {
      bf16x8 af[4], bfr[4];
#pragma unroll
      for (int i = 0; i < 4; ++i) {
        const int row = wr + i * 16 + lr;
        af[i] = *(const bf16x8*)&As[row][(((kk << 2) | lq) ^ (row & 7)) << 3];
      }
#pragma unroll
      for (int j = 0; j < 4; ++j) {
        const int row = wc + j * 16 + lr;
        bfr[j] = *(const bf16x8*)&Bs[row][(((kk << 2) | lq) ^ (row & 7)) << 3];
      }
#pragma unroll
      for (int i = 0; i < 4; ++i)
#pragma unroll
        for (int j = 0; j < 4; ++j)
          acc[i][j] = __builtin_amdgcn_mfma_f32_16x16x32_bf16(af[i], bfr[j], acc[i][j], 0, 0, 0);
    }
  }

  const int lg4 = lq * 4;
#pragma unroll
  for (int i = 0; i < 4; ++i) {
    const int grow0 = bx * 128 + wr + i * 16 + lg4;
#pragma unroll
    for (int j = 0; j < 4; ++j) {
      const int gcol = by * 128 + wc + j * 16 + lr;
      float bv = 0.f;
      if (EPI == 1) bv = bias[gcol];
#pragma unroll
      for (int r = 0; r < 4; ++r) {
        float v = acc[i][j][r];
        if (EPI == 0) {
          C[(size_t)(grow0 + r) * N + gcol] = v;
        } else if (EPI == 1) {
          v += bv;
          v = fmaxf(v, 0.f) + log1pf(expf(-fabsf(v)));   // stable softplus
          Cbf[(size_t)(grow0 + r) * N + gcol] = f2bf(v);
        } else {
          Cbf[(size_t)(grow0 + r) * N + gcol] = f2bf(v);
        }
      }
    }
  }
}

// ---------------------------------------------------------------------------
// x_proj split-K 16: A=ubf[2048,2048], BT=WxT[128,2048] (both ld 2048).
// grid (16, 16): bx = row-tile, ch = K-chunk of 128. Partials stored BF16
// to P[r][96] (padding cols 96-127 are zeros — not written).
// ---------------------------------------------------------------------------
__global__ __launch_bounds__(256)
void xproj_split(const u16* __restrict__ A, const u16* __restrict__ BT,
                 u16* __restrict__ P) {
  __shared__ u16 As[128][64];
  __shared__ u16 Bs[128][64];
  const int t = threadIdx.x;
  const int l = t & 63;
  const int w = t >> 6;
  const int wr = (w >> 1) * 64;
  const int wc = (w & 1) * 64;
  const int bx = blockIdx.x;
  const int ch = blockIdx.y;
  const int kb = ch * 128;

  const size_t aoff = (size_t)bx * 128 * 2048 + kb;
  const int r0 = t >> 3;
  const int c0s = (((t & 7) ^ (r0 & 7)) << 3);
  const int c0l = (t & 7) << 3;
  const int lr = l & 15;
  const int lq = l >> 4;

  f32x4 acc[4][4];
#pragma unroll
  for (int i = 0; i < 4; ++i)
#pragma unroll
    for (int j = 0; j < 4; ++j) acc[i][j] = (f32x4){0.f, 0.f, 0.f, 0.f};

  for (int kt = 0; kt < 128; kt += 64) {
    __syncthreads();
#pragma unroll
    for (int i = 0; i < 4; ++i) {
      const int r = r0 + i * 32;
      gload_lds16(A + aoff + (size_t)r * 2048 + kt + c0s, &As[r][c0l]);
      gload_lds16(BT + (size_t)r * 2048 + kb + kt + c0s, &Bs[r][c0l]);
    }
    __syncthreads();
#pragma unroll
    for (int kk = 0; kk < 2; ++kk) {
      bf16x8 af[4], bfr[4];
#pragma unroll
      for (int i = 0; i < 4; ++i) {
        const int row = wr + i * 16 + lr;
        af[i] = *(const bf16x8*)&As[row][(((kk << 2) | lq) ^ (row & 7)) << 3];
      }
#pragma unroll
      for (int j = 0; j < 4; ++j) {
        const int row = wc + j * 16 + lr;
        bfr[j] = *(const bf16x8*)&Bs[row][(((kk << 2) | lq) ^ (row & 7)) << 3];
      }
#pragma unroll
      for (int i = 0; i < 4; ++i)
#pragma unroll
        for (int j = 0; j < 4; ++j)
          acc[i][j] = __builtin_amdgcn_mfma_f32_16x16x32_bf16(af[i], bfr[j], acc[i][j], 0, 0, 0);
    }
  }

  u16* __restrict__ Pc = P + (size_t)ch * 196608;   // 2048*96
  const int lg4 = lq * 4;
#pragma unroll
  for (int i = 0; i < 4; ++i) {
    const int grow0 = bx * 128 + wr + i * 16 + lg4;
#pragma unroll
    for (int j = 0; j < 4; ++j) {
      const int gcol = wc + j * 16 + lr;
      if (gcol < 96) {
#pragma unroll
        for (int r = 0; r < 4; ++r)
          Pc[(size_t)(grow0 + r) * 96 + gcol] = f2bf(acc[i][j][r]);
      }
    }
  }
}

// merge 16 bf16 x_proj partials -> dtbf bf16 [r][64] + compact dbc32 f32 [r][32]
__global__ __launch_bounds__(256)
void merge_x(const u16* __restrict__ P, float* __restrict__ dbc32,
             u16* __restrict__ dtbf) {
  const int idx = blockIdx.x * 256 + threadIdx.x;   // 196608
  float s = 0.f;
#pragma unroll
  for (int ch = 0; ch < 16; ++ch) s += bf2f(P[(size_t)ch * 196608 + idx]);
  const int r = idx / 96, c = idx - r * 96;
  if (c < 64) dtbf[r * 64 + c] = f2bf(s);
  else        dbc32[r * 32 + (c - 64)] = s;
}

// ---------------------------------------------------------------------------
// out_proj split-K 4: A=ybf[2048,2048], BT=WoT[1024,2048] (ld 2048).
// grid (16, 32): bx = row-tile, y&7 = N-tile, y>>3 = K-quarter of 512.
// Partials stored BF16.
// ---------------------------------------------------------------------------
__global__ __launch_bounds__(256)
void outproj_split(const u16* __restrict__ A, const u16* __restrict__ BT,
                   u16* __restrict__ P) {
  __shared__ u16 As[128][64];
  __shared__ u16 Bs[128][64];
  const int t = threadIdx.x;
  const int l = t & 63;
  const int w = t >> 6;
  const int wr = (w >> 1) * 64;
  const int wc = (w & 1) * 64;
  const int bx = blockIdx.x;
  const int byn = blockIdx.y & 7;
  const int ch = blockIdx.y >> 3;      // 0..3
  const int kb = ch * 512;

  const size_t aoff = (size_t)bx * 128 * 2048 + kb;
  const size_t boff = (size_t)byn * 128 * 2048 + kb;
  const int r0 = t >> 3;
  const int c0s = (((t & 7) ^ (r0 & 7)) << 3);
  const int c0l = (t & 7) << 3;
  const int lr = l & 15;
  const int lq = l >> 4;

  f32x4 acc[4][4];
#pragma unroll
  for (int i = 0; i < 4; ++i)
#pragma unroll
    for (int j = 0; j < 4; ++j) acc[i][j] = (f32x4){0.f, 0.f, 0.f, 0.f};

  for (int kt = 0; kt < 512; kt += 64) {
    __syncthreads();
#pragma unroll
    for (int i = 0; i < 4; ++i) {
      const int r = r0 + i * 32;
      gload_lds16(A + aoff + (size_t)r * 2048 + kt + c0s, &As[r][c0l]);
      gload_lds16(BT + boff + (size_t)r * 2048 + kt + c0s, &Bs[r][c0l]);
    }
    __syncthreads();
#pragma unroll
    for (int kk = 0; kk < 2; ++kk) {
      bf16x8 af[4], bfr[4];
#pragma unroll
      for (int i = 0; i < 4; ++i) {
        const int row = wr + i * 16 + lr;
        af[i] = *(const bf16x8*)&As[row][(((kk << 2) | lq) ^ (row & 7)) << 3];
      }
#pragma unroll
      for (int j = 0; j < 4; ++j) {
        const int row = wc + j * 16 + lr;
        bfr[j] = *(const bf16x8*)&Bs[row][(((kk << 2) | lq) ^ (row & 7)) << 3];
      }
#pragma unroll
      for (int i = 0; i < 4; ++i)
#pragma unroll
        for (int j = 0; j < 4; ++j)
          acc[i][j] = __builtin_amdgcn_mfma_f32_16x16x32_bf16(af[i], bfr[j], acc[i][j], 0, 0, 0);
    }
  }

  u16* __restrict__ Pc = P + (size_t)ch * 2097152;
  const int lg4 = lq * 4;
#pragma unroll
  for (int i = 0; i < 4; ++i) {
    const int grow0 = bx * 128 + wr + i * 16 + lg4;
#pragma unroll
    for (int j = 0; j < 4; ++j) {
      const int gcol = byn * 128 + wc + j * 16 + lr;
#pragma unroll
      for (int r = 0; r < 4; ++r)
        Pc[(size_t)(grow0 + r) * 1024 + gcol] = f2bf(acc[i][j][r]);
    }
  }
}

// layer-1 merge: xbf = bf16(p0+p1+p2+p3), partials bf16
__global__ __launch_bounds__(256)
void merge_o1(const u16* __restrict__ P, u16* __restrict__ xbf) {
  const int i4 = (blockIdx.x * 256 + threadIdx.x) * 4;   // 2048 blocks
  float v0 = 0.f, v1 = 0.f, v2 = 0.f, v3 = 0.f;
#pragma unroll
  for (int ch = 0; ch < 4; ++ch) {
    const u16x4 b = *(const u16x4*)(P + (size_t)ch * 2097152 + i4);
    v0 += bf2f(b[0]); v1 += bf2f(b[1]); v2 += bf2f(b[2]); v3 += bf2f(b[3]);
  }
  u16x4 o = { f2bf(v0), f2bf(v1), f2bf(v2), f2bf(v3) };
  *(u16x4*)(xbf + i4) = o;
}

// layer-2 merge + final LayerNorm fused: xlnbf = bf16(LN(sum of 4 bf16 partials))
__global__ __launch_bounds__(256)
void merge_o2_ln(const u16* __restrict__ P, const float* __restrict__ g,
                 const float* __restrict__ bta, u16* __restrict__ out) {
  __shared__ float red1[4], red2[4];
  const int r = blockIdx.x;
  const int tid = threadIdx.x;
  const int lane = tid & 63, wid = tid >> 6;
  const int c4 = tid * 4;
  float v0 = 0.f, v1 = 0.f, v2 = 0.f, v3 = 0.f;
#pragma unroll
  for (int ch = 0; ch < 4; ++ch) {
    const u16x4 b = *(const u16x4*)(P + (size_t)ch * 2097152 + (size_t)r * 1024 + c4);
    v0 += bf2f(b[0]); v1 += bf2f(b[1]); v2 += bf2f(b[2]); v3 += bf2f(b[3]);
  }
  float s = v0 + v1 + v2 + v3;
#pragma unroll
  for (int m = 1; m < 64; m <<= 1) s += __shfl_xor(s, m, 64);
  if (lane == 0) red1[wid] = s;
  __syncthreads();
  const float mu = (red1[0] + red1[1] + red1[2] + red1[3]) * (1.f / 1024.f);
  const float d0 = v0 - mu, d1 = v1 - mu, d2 = v2 - mu, d3 = v3 - mu;
  float qv = d0 * d0 + d1 * d1 + d2 * d2 + d3 * d3;
#pragma unroll
  for (int m = 1; m < 64; m <<= 1) qv += __shfl_xor(qv, m, 64);
  if (lane == 0) red2[wid] = qv;
  __syncthreads();
  const float rs = rsqrtf((red2[0] + red2[1] + red2[2] + red2[3]) * (1.f / 1024.f) + 1e-5f);
  const float4 gv = *(const float4*)(g + c4);
  const float4 bv = *(const float4*)(bta + c4);
  u16x4 o = { f2bf(d0 * rs * gv.x + bv.x), f2bf(d1 * rs * gv.y + bv.y),
              f2bf(d2 * rs * gv.z + bv.z), f2bf(d3 * rs * gv.w + bv.w) };
  *(u16x4*)(out + (size_t)r * 1024 + c4) = o;
}

// ---------------------------------------------------------------------------
// mega prep batch: 64x64 tiles; 256B-contiguous NT reads, u16x8 stores.
// tx<0: embed gather (lt = row).
// ---------------------------------------------------------------------------
struct TBatch {
  const float* src[10];
  u16* dst[10];
  int K[10], N[10], tx[10];
  int start[11];
  int njobs;
  const int* ids;
};

__global__ __launch_bounds__(256)
void transpose_batch(TBatch tb) {
  const int tile = blockIdx.x;
  int j = 0;
  while (j + 1 < tb.njobs && tile >= tb.start[j + 1]) ++j;
  const int lt = tile - tb.start[j];

  if (tb.tx[j] < 0) {   // embed gather: row lt, 1024 cols via float4
    const int c = threadIdx.x * 4;
    const int id = tb.ids[lt];
    const float4 v = *(const float4*)(tb.src[j] + (size_t)id * 1024 + c);
    u16x4 o = { f2bf(v.x), f2bf(v.y), f2bf(v.z), f2bf(v.w) };
    *(u16x4*)(tb.dst[j] + (size_t)lt * 1024 + c) = o;
    return;
  }

  const int K = tb.K[j];
  const int N = tb.N[j];
  const int kb = (lt % tb.tx[j]) * 64;
  const int nb = (lt / tb.tx[j]) * 64;
  const float* __restrict__ in = tb.src[j];
  u16* __restrict__ out = tb.dst[j];

  __shared__ float ts[64][65];
  const int rr = threadIdx.x >> 4;        // 0..15
  const int cc = (threadIdx.x & 15) * 4;  // 0..60
  const int gn = nb + cc;
#pragma unroll
  for (int s = 0; s < 4; ++s) {
    const int k = kb + s * 16 + rr;
    f32x4 v = { 0.f, 0.f, 0.f, 0.f };
    if (gn < N) v = __builtin_nontemporal_load((const f32x4*)(in + (size_t)k * N + gn));
    ts[s * 16 + rr][cc + 0] = v[0];
    ts[s * 16 + rr][cc + 1] = v[1];
    ts[s * 16 + rr][cc + 2] = v[2];
    ts[s * 16 + rr][cc + 3] = v[3];
  }
  __syncthreads();
  const int k8 = (threadIdx.x & 7) * 8;
#pragma unroll
  for (int s = 0; s < 2; ++s) {
    const int nl = (threadIdx.x >> 3) + s * 32;   // 0..63
    u16x8 o;
#pragma unroll
    for (int i = 0; i < 8; ++i) o[i] = f2bf(ts[k8 + i][nl]);
    *(u16x8*)(out + (size_t)(nb + nl) * K + kb + k8) = o;
  }
}

// u = silu(causal_conv(xin) + cb) -> bf16.  xz is bf16. 4 ch/thread.
__global__ __launch_bounds__(256)
void conv_silu4(const u16* __restrict__ xzb, const float* __restrict__ cw,
                const float* __restrict__ cb, u16* __restrict__ ubf) {
  const int i4 = (blockIdx.x * 256 + threadIdx.x) * 4;   // grid 4096
  const int d = i4 & 2047;
  const int r = i4 >> 11;
  const int t = r & 1023;
  float4 acc = *(const float4*)(cb + d);
  const float4 w0 = *(const float4*)(cw + (d + 0) * 4);
  const float4 w1 = *(const float4*)(cw + (d + 1) * 4);
  const float4 w2 = *(const float4*)(cw + (d + 2) * 4);
  const float4 w3 = *(const float4*)(cw + (d + 3) * 4);
#pragma unroll
  for (int k = 0; k < 4; ++k) {
    const int tt = t - 3 + k;
    if (tt >= 0) {
      const u16x4 x4 = *(const u16x4*)(xzb + (size_t)(r - 3 + k) * 4096 + d);
      acc.x = fmaf(bf2f(x4[0]), ((const float*)&w0)[k], acc.x);
      acc.y = fmaf(bf2f(x4[1]), ((const float*)&w1)[k], acc.y);
      acc.z = fmaf(bf2f(x4[2]), ((const float*)&w2)[k], acc.z);
      acc.w = fmaf(bf2f(x4[3]), ((const float*)&w3)[k], acc.w);
    }
  }
  u16x4 o = { f2bf(acc.x / (1.f + __expf(-acc.x))), f2bf(acc.y / (1.f + __expf(-acc.y))),
              f2bf(acc.z / (1.f + __expf(-acc.z))), f2bf(acc.w / (1.f + __expf(-acc.w))) };
  *(u16x4*)(ubf + i4) = o;
}

// ---------------------------------------------------------------------------
// selective scan, n-in-registers; delta/u/z read as bf16 (coalesced 2B/lane).
// 32 chunks x 32 steps; grid = 2b x 8dt x 32ch = 512 blocks (2 blocks/CU).
// dbc32 compact layout [r][32]: B = cols 0-15, C = cols 16-31.
// Chunk-state buffers Pb/Qb/Hp stored as bf16.
// ---------------------------------------------------------------------------
__global__ __launch_bounds__(256)
void scan_pass1(const u16* __restrict__ deltab, const u16* __restrict__ ub,
                const float* __restrict__ dbc32, const float* __restrict__ A_log,
                u16* __restrict__ Pb, u16* __restrict__ Qb) {
  const int blk = blockIdx.x;
  const int ch = blk & 31;
  if (ch == 31) return;          // last chunk's (P,Q) never consumed
  const int dt = (blk >> 5) & 7;
  const int b = blk >> 8;
  const int d = dt * 256 + threadIdx.x;

  float Ac[16], h[16], P[16];
#pragma unroll
  for (int n = 0; n < 16; ++n) {
    Ac[n] = -expf(A_log[d * 16 + n]) * 1.44269504f;
    h[n] = 0.f;
    P[n] = 1.f;
  }
  const int r0 = b * 1024 + ch * 32;
  for (int j = 0; j < 32; ++j) {
    const size_t r = r0 + j;
    const float dlt = bf2f(deltab[r * 2048 + d]);
    const float uu = bf2f(ub[r * 2048 + d]);
    const float du = dlt * uu;
    const float4 B0 = *(const float4*)(dbc32 + r * 32 + 0);
    const float4 B1 = *(const float4*)(dbc32 + r * 32 + 4);
    const float4 B2 = *(const float4*)(dbc32 + r * 32 + 8);
    const float4 B3 = *(const float4*)(dbc32 + r * 32 + 12);
    const float Bv[16] = { B0.x, B0.y, B0.z, B0.w, B1.x, B1.y, B1.z, B1.w,
                           B2.x, B2.y, B2.z, B2.w, B3.x, B3.y, B3.z, B3.w };
#pragma unroll
    for (int n = 0; n < 16; ++n) {
      const float da = exp2f(dlt * Ac[n]);
      P[n] *= da;
      h[n] = fmaf(da, h[n], du * Bv[n]);
    }
  }
  const size_t o = ((size_t)ch * 4096 + b * 2048 + d) * 16;
  u16x8 p0, p1, q0, q1;
#pragma unroll
  for (int n = 0; n < 8; ++n) { p0[n] = f2bf(P[n]); p1[n] = f2bf(P[n + 8]);
                                q0[n] = f2bf(h[n]); q1[n] = f2bf(h[n + 8]); }
  *(u16x8*)(Pb + o) = p0; *(u16x8*)(Pb + o + 8) = p1;
  *(u16x8*)(Qb + o) = q0; *(u16x8*)(Qb + o + 8) = q1;
}

// fold chunk (P,Q) into per-chunk entry states: Hp[ch] = state entering ch.
__global__ __launch_bounds__(256)
void scan_prefix(const u16* __restrict__ Pb, const u16* __restrict__ Qb,
                 u16* __restrict__ Hp) {
  const int tid = blockIdx.x * 256 + threadIdx.x;   // 65536
  float h = 0.f;
  Hp[tid] = 0;
  for (int ch = 0; ch < 31; ++ch) {
    const size_t o = (size_t)ch * 65536 + tid;
    h = fmaf(bf2f(Pb[o]), h, bf2f(Qb[o]));
    Hp[o + 65536] = f2bf(h);
  }
}

__global__ __launch_bounds__(256)
void scan_pass2(const u16* __restrict__ deltab, const u16* __restrict__ ub,
                const float* __restrict__ dbc32, const u16* __restrict__ xzb,
                const float* __restrict__ A_log, const float* __restrict__ Dp,
                const u16* __restrict__ Hp, u16* __restrict__ ybf) {
  const int blk = blockIdx.x;
  const int ch = blk & 31;
  const int dt = (blk >> 5) & 7;
  const int b = blk >> 8;
  const int d = dt * 256 + threadIdx.x;

  float Ac[16], h[16];
  const size_t ho = ((size_t)ch * 4096 + b * 2048 + d) * 16;
#pragma unroll
  for (int n = 0; n < 16; ++n) {
    Ac[n] = -expf(A_log[d * 16 + n]) * 1.44269504f;
    h[n] = bf2f(Hp[ho + n]);
  }
  const float Dd = Dp[d];

  const int r0 = b * 1024 + ch * 32;
  for (int j = 0; j < 32; ++j) {
    const size_t r = r0 + j;
    const float dlt = bf2f(deltab[r * 2048 + d]);
    const float uu = bf2f(ub[r * 2048 + d]);
    const float zz = bf2f(xzb[r * 4096 + 2048 + d]);
    const float du = dlt * uu;
    const float4 B0 = *(const float4*)(dbc32 + r * 32 + 0);
    const float4 B1 = *(const float4*)(dbc32 + r * 32 + 4);
    const float4 B2 = *(const float4*)(dbc32 + r * 32 + 8);
    const float4 B3 = *(const float4*)(dbc32 + r * 32 + 12);
    const float4 C0 = *(const float4*)(dbc32 + r * 32 + 16);
    const float4 C1 = *(const float4*)(dbc32 + r * 32 + 20);
    const float4 C2 = *(const float4*)(dbc32 + r * 32 + 24);
    const float4 C3 = *(const float4*)(dbc32 + r * 32 + 28);
    const float Bv[16] = { B0.x, B0.y, B0.z, B0.w, B1.x, B1.y, B1.z, B1.w,
                           B2.x, B2.y, B2.z, B2.w, B3.x, B3.y, B3.z, B3.w };
    const float Cv[16] = { C0.x, C0.y, C0.z, C0.w, C1.x, C1.y, C1.z, C1.w,
                           C2.x, C2.y, C2.z, C2.w, C3.x, C3.y, C3.z, C3.w };
    float p0 = 0.f, p1 = 0.f, p2 = 0.f, p3 = 0.f;
#pragma unroll
    for (int n = 0; n < 16; n += 4) {
      float da;
      da = exp2f(dlt * Ac[n + 0]); h[n + 0] = fmaf(da, h[n + 0], du * Bv[n + 0]); p0 = fmaf(h[n + 0], Cv[n + 0], p0);
      da = exp2f(dlt * Ac[n + 1]); h[n + 1] = fmaf(da, h[n + 1], du * Bv[n + 1]); p1 = fmaf(h[n + 1], Cv[n + 1], p1);
      da = exp2f(dlt * Ac[n + 2]); h[n + 2] = fmaf(da, h[n + 2], du * Bv[n + 2]); p2 = fmaf(h[n + 2], Cv[n + 2], p2);
      da = exp2f(dlt * Ac[n + 3]); h[n + 3] = fmaf(da, h[n + 3], du * Bv[n + 3]); p3 = fmaf(h[n + 3], Cv[n + 3], p3);
    }
    const float p = (p0 + p1) + (p2 + p3);
    const float yv = (p + uu * Dd) * (zz / (1.f + __expf(-zz)));
    ybf[r * 2048 + d] = f2bf(yv);
  }
}

// ---------------------------------------------------------------------------
extern "C" void kernel_launch(void* const* d_in, const int* in_sizes, int n_in,
                              void* d_out, int out_size, void* d_ws, size_t ws_size,
                              hipStream_t stream) {
  (void)in_sizes; (void)n_in; (void)out_size; (void)ws_size;
  const int*   ids      = (const int*)d_in[0];
  const float* embed    = (const float*)d_in[1];
  const float* in_proj  = (const float*)d_in[2];
  const float* conv_w   = (const float*)d_in[3];
  const float* conv_b   = (const float*)d_in[4];
  const float* x_proj   = (const float*)d_in[5];
  const float* dt_w     = (const float*)d_in[6];
  const float* dt_b     = (const float*)d_in[7];
  const float* A_log    = (const float*)d_in[8];
  const float* Dp       = (const float*)d_in[9];
  const float* out_proj = (const float*)d_in[10];
  const float* ln_g     = (const float*)d_in[11];
  const float* ln_bta   = (const float*)d_in[12];
  const float* head     = (const float*)d_in[13];

  // f32 scratch inside d_out (all consumed before head GEMM overwrites)
  float* fout  = (float*)d_out;
  float* dbc32 = fout + 16777216;   // 65,536 f32

  // bf16 scratch in the dead tail of d_out (dead before head GEMM writes)
  u16* tail = (u16*)(fout + 17300000);
  u16* WiT[2]  = { tail,                tail + 4194304 };
  u16* WxT[2]  = { tail + 8388608,      tail + 8650752 };
  u16* WdtT[2] = { tail + 8912896,      tail + 9043968 };
  u16* WoT[2]  = { tail + 9175040,      tail + 11272192 };
  u16* dbf     = tail + 13369344;      // 4,194,304 u16 (bf16 delta)
  u16* xzb     = tail + 17563648;      // 8,388,608 u16
  u16* Pbh     = tail + 25952256;      // 2,097,152 u16 (bf16 chunk P)
  u16* Qbh     = tail + 28049408;      // 2,097,152 u16 (bf16 chunk Q)
  u16* Hph     = tail + 30146560;      // 2,097,152 u16 (bf16 entry state)
  u16* oppb    = tail + 32243712;      // 8,388,608 u16 (bf16 out_proj partials)
  u16* xppb    = tail + 40632320;      // 16*196,608 = 3,145,728 u16 (bf16 x_proj partials)
                                       // ends 43,778,048 u16 = 21,889,024 f32
                                       // 17.3M + 21.9M = 39.2M f32 < 65.5M f32 ✓

  // bf16 scratch in d_ws
  char* wp = (char*)d_ws;
  u16* headT = (u16*)wp; wp += (size_t)32000 * 1024 * 2;
  u16* xbf   = (u16*)wp; wp += (size_t)2048 * 1024 * 2;
  u16* ubf   = (u16*)wp; wp += (size_t)2048 * 2048 * 2;
  u16* dtbf  = (u16*)wp; wp += (size_t)2048 * 64 * 2;
  u16* ybf   = (u16*)wp; wp += (size_t)2048 * 2048 * 2;
  u16* xlnbf = (u16*)wp; wp += (size_t)2048 * 1024 * 2;

  const dim3 tb(256);
  const dim3 tb5(512);

  // ---- one mega prep launch: head + all layer weights + embed gather ----
  TBatch t{};
  int nj = 0, acc = 0;
  t.ids = ids;
  t.src[nj] = head; t.dst[nj] = headT;
  t.K[nj] = 1024; t.N[nj] = 32000; t.tx[nj] = 16;
  t.start[nj] = acc; acc += 16 * 500; ++nj;
  for (int i = 0; i < 2; ++i) {
    t.src[nj] = in_proj + (size_t)i * 1024 * 4096; t.dst[nj] = WiT[i];
    t.K[nj] = 1024; t.N[nj] = 4096; t.tx[nj] = 16;
    t.start[nj] = acc; acc += 16 * 64; ++nj;
    t.src[nj] = x_proj + (size_t)i * 2048 * 96; t.dst[nj] = WxT[i];
    t.K[nj] = 2048; t.N[nj] = 96; t.tx[nj] = 32;
    t.start[nj] = acc; acc += 32 * 2; ++nj;
    t.src[nj] = dt_w + (size_t)i * 64 * 2048; t.dst[nj] = WdtT[i];
    t.K[nj] = 64; t.N[nj] = 2048; t.tx[nj] = 1;
    t.start[nj] = acc; acc += 1 * 32; ++nj;
    t.src[nj] = out_proj + (size_t)i * 2048 * 1024; t.dst[nj] = WoT[i];
    t.K[nj] = 2048; t.N[nj] = 1024; t.tx[nj] = 32;
    t.start[nj] = acc; acc += 32 * 16; ++nj;
  }
  t.src[nj] = embed; t.dst[nj] = xbf;
  t.K[nj] = 0; t.N[nj] = 0; t.tx[nj] = -1;
  t.start[nj] = acc; acc += 2048; ++nj;
  t.start[nj] = acc;
  t.njobs = nj;
  transpose_batch<<<acc, tb, 0, stream>>>(t);

  for (int i = 0; i < 2; ++i) {
    gemm_bt<2><<<dim3(16, 32), tb, 0, stream>>>(xbf, WiT[i], nullptr, xzb, nullptr, 2048, 4096, 1024);
    conv_silu4<<<4096, tb, 0, stream>>>(xzb, conv_w + i * 2048 * 4, conv_b + i * 2048, ubf);
    xproj_split<<<dim3(16, 16), tb, 0, stream>>>(ubf, WxT[i], xppb);
    merge_x<<<768, tb, 0, stream>>>(xppb, dbc32, dtbf);
    gemm_bt<1><<<dim3(16, 16), tb, 0, stream>>>(dtbf, WdtT[i], nullptr, dbf, dt_b + i * 2048, 2048, 2048, 64);
    scan_pass1<<<512, tb, 0, stream>>>(dbf, ubf, dbc32, A_log + i * 2048 * 16, Pbh, Qbh);
    scan_prefix<<<256, tb, 0, stream>>>(Pbh, Qbh, Hph);
    scan_pass2<<<512, tb, 0, stream>>>(dbf, ubf, dbc32, xzb, A_log + i * 2048 * 16, Dp + i * 2048, Hph, ybf);
    outproj_split<<<dim3(16, 32), tb, 0, stream>>>(ybf, WoT[i], oppb);
    if (i == 0) {
      merge_o1<<<2048, tb, 0, stream>>>(oppb, xbf);
    } else {
      merge_o2_ln<<<2048, tb, 0, stream>>>(oppb, ln_g, ln_bta, xlnbf);
    }
  }

  gemm256<<<dim3(8, 125), tb5, 0, stream>>>(xlnbf, headT, fout, 2048, 32000, 1024);
}